// Round 5
// baseline (173.463 us; speedup 1.0000x reference)
//
#include <hip/hip_runtime.h>
#include <math.h>

#define B_ 2
#define H_ 512
#define W_ 512
#define HW_ (H_ * W_)
#define NCH_IN 48
#define NCH_OUT 22
#define DEG_ 57.29577951308232f

__device__ __forceinline__ float frcp(float x)  { return __builtin_amdgcn_rcpf(x); }
// Newton-refined reciprocal: ~2^-28 relative
__device__ __forceinline__ float frcp_nr(float x) {
    float r = __builtin_amdgcn_rcpf(x);
    return r * __builtin_fmaf(-x, r, 2.0f);
}
__device__ __forceinline__ float fsqrtf_(float x){ return __builtin_amdgcn_sqrtf(x); }

__device__ __forceinline__ float fast_acos(float x) {
    float ax = fabsf(x);
    float t = fsqrtf_(fmaxf(1.0f - ax, 0.0f));
    float p = t * (1.5707288f + ax * (-0.2121144f + ax * (0.0742610f + ax * (-0.0187293f))));
    return (x >= 0.0f) ? p : (3.14159265358979f - p);
}

__device__ __forceinline__ float fast_atan2(float y, float x) {
    float ay = fabsf(y), ax = fabsf(x);
    float mx = fmaxf(ax, ay), mn = fminf(ax, ay);
    float a = mn * frcp(fmaxf(mx, 1e-37f));
    float s = a * a;
    float r = a * (0.99997726f + s * (-0.33262347f + s * (0.19354346f +
              s * (-0.11643287f + s * (0.05265332f + s * (-0.01172120f))))));
    if (ay > ax) r = 1.57079632679f - r;
    if (x < 0.0f) r = 3.14159265359f - r;
    return (y < 0.0f) ? -r : r;
}

__device__ __forceinline__ unsigned int fkey(float f) {
    unsigned int u = __float_as_uint(f);
    return (u & 0x80000000u) ? ~u : (u | 0x80000000u);
}
__device__ __forceinline__ float funkey(unsigned int k) {
    return (k & 0x80000000u) ? __uint_as_float(k ^ 0x80000000u) : __uint_as_float(~k);
}

// mm[2b] = max of ~fkey(v) (decodes to min), mm[2b+1] = max of fkey(v); zero-init by memset.
// float4 vector loads: channel 0 of each batch is 1 MB contiguous.
__global__ __launch_bounds__(256) void minmax_kernel(const float* __restrict__ x,
                                                     unsigned int* __restrict__ mm) {
    int b = blockIdx.x >> 5;        // 32 blocks per batch
    int blk = blockIdx.x & 31;
    const float4* src = (const float4*)(x + (size_t)b * NCH_IN * HW_);
    float lo = INFINITY, hi = -INFINITY;
    for (int i = blk * 256 + threadIdx.x; i < HW_ / 4; i += 32 * 256) {
        float4 v = src[i];
        lo = fminf(lo, fminf(fminf(v.x, v.y), fminf(v.z, v.w)));
        hi = fmaxf(hi, fmaxf(fmaxf(v.x, v.y), fmaxf(v.z, v.w)));
    }
    __shared__ float slo[256], shi[256];
    slo[threadIdx.x] = lo; shi[threadIdx.x] = hi;
    __syncthreads();
    for (int s = 128; s > 0; s >>= 1) {
        if (threadIdx.x < s) {
            slo[threadIdx.x] = fminf(slo[threadIdx.x], slo[threadIdx.x + s]);
            shi[threadIdx.x] = fmaxf(shi[threadIdx.x], shi[threadIdx.x + s]);
        }
        __syncthreads();
    }
    if (threadIdx.x == 0) {
        atomicMax(&mm[2 * b], ~fkey(slo[0]));
        atomicMax(&mm[2 * b + 1], fkey(shi[0]));
    }
}

// X = A^-1 * B, Gauss-Jordan with partial pivoting on [A|B] (branchless swaps).
// Dead columns (<k) skipped.
__device__ __forceinline__ void solve4(const float A[4][4], const float Bm[4][4], float X[4][4]) {
    float m[4][8];
#pragma unroll
    for (int i = 0; i < 4; i++) {
#pragma unroll
        for (int j = 0; j < 4; j++) { m[i][j] = A[i][j]; m[i][j + 4] = Bm[i][j]; }
    }
#pragma unroll
    for (int k = 0; k < 4; k++) {
#pragma unroll
        for (int r = k + 1; r < 4; r++) {
            bool sw = fabsf(m[r][k]) > fabsf(m[k][k]);
#pragma unroll
            for (int c = k; c < 8; c++) {
                float a = m[k][c], b = m[r][c];
                m[k][c] = sw ? b : a;
                m[r][c] = sw ? a : b;
            }
        }
        float piv = frcp_nr(m[k][k]);
#pragma unroll
        for (int c = k + 1; c < 8; c++) m[k][c] *= piv;
#pragma unroll
        for (int r = 0; r < 4; r++) {
            if (r == k) continue;
            float f = m[r][k];
#pragma unroll
            for (int c = k + 1; c < 8; c++)
                m[r][c] = __builtin_fmaf(-f, m[k][c], m[r][c]);
        }
    }
#pragma unroll
    for (int i = 0; i < 4; i++)
#pragma unroll
        for (int j = 0; j < 4; j++) X[i][j] = m[i][j + 4];
}

__device__ __forceinline__ void mul4(const float A[4][4], const float B[4][4], float C[4][4]) {
#pragma unroll
    for (int i = 0; i < 4; i++)
#pragma unroll
        for (int j = 0; j < 4; j++) {
            float s = 0.0f;
#pragma unroll
            for (int k = 0; k < 4; k++) s += A[i][k] * B[k][j];
            C[i][j] = s;
        }
}

__device__ __forceinline__ void inv3(const float A[3][3], float out[3][3]) {
    float c00 = A[1][1] * A[2][2] - A[1][2] * A[2][1];
    float c01 = A[1][2] * A[2][0] - A[1][0] * A[2][2];
    float c02 = A[1][0] * A[2][1] - A[1][1] * A[2][0];
    float det = A[0][0] * c00 + A[0][1] * c01 + A[0][2] * c02;
    float id = frcp_nr(det);
    out[0][0] = c00 * id;
    out[0][1] = (A[0][2] * A[2][1] - A[0][1] * A[2][2]) * id;
    out[0][2] = (A[0][1] * A[1][2] - A[0][2] * A[1][1]) * id;
    out[1][0] = c01 * id;
    out[1][1] = (A[0][0] * A[2][2] - A[0][2] * A[2][0]) * id;
    out[1][2] = (A[0][2] * A[1][0] - A[0][0] * A[1][2]) * id;
    out[2][0] = c02 * id;
    out[2][1] = (A[0][1] * A[2][0] - A[0][0] * A[2][1]) * id;
    out[2][2] = (A[0][0] * A[1][1] - A[0][1] * A[1][0]) * id;
}

__device__ __forceinline__ float det3(const float A[3][3]) {
    return A[0][0] * (A[1][1] * A[2][2] - A[1][2] * A[2][1])
         - A[0][1] * (A[1][0] * A[2][2] - A[1][2] * A[2][0])
         + A[0][2] * (A[1][0] * A[2][1] - A[1][1] * A[2][0]);
}

__device__ __forceinline__ void eig3_sym(const float A[3][3], float& l1, float& l2, float& l3) {
    float q = (A[0][0] + A[1][1] + A[2][2]) * (1.0f / 3.0f);
    float a00 = A[0][0] - q, a11 = A[1][1] - q, a22 = A[2][2] - q;
    float off = A[0][1] * A[0][1] + A[0][2] * A[0][2] + A[1][2] * A[1][2];
    float p2 = a00 * a00 + a11 * a11 + a22 * a22 + 2.0f * off;
    float p = fsqrtf_(p2 * (1.0f / 6.0f) + 1e-30f);
    float inv = frcp(p);
    float b00 = a00 * inv, b11 = a11 * inv, b22 = a22 * inv;
    float b01 = A[0][1] * inv, b02 = A[0][2] * inv, b12 = A[1][2] * inv;
    float detB = b00 * (b11 * b22 - b12 * b12)
               - b01 * (b01 * b22 - b12 * b02)
               + b02 * (b01 * b12 - b11 * b02);
    float r = 0.5f * detB;
    r = fminf(fmaxf(r, -1.0f), 1.0f);
    float phi = fast_acos(r) * (1.0f / 3.0f);
    l1 = q + 2.0f * p * __cosf(phi);
    l3 = q + 2.0f * p * __cosf(phi + 2.0943951023931953f);
    l2 = 3.0f * q - l1 - l3;
}

__global__ __launch_bounds__(256) void main_kernel(const float* __restrict__ x,
                                                   const unsigned int* __restrict__ mmk,
                                                   float* __restrict__ out) {
    int idx = blockIdx.x * 256 + threadIdx.x;
    if (idx >= B_ * HW_) return;
    int b = idx / HW_;
    int p = idx - b * HW_;
    const float* src = x + (size_t)b * NCH_IN * HW_ + p;

    // plain (cacheable) loads: input is L2/LLC-warm from the harness restore
    float F[4][4], A[4][4], WT[4][4];
#pragma unroll
    for (int i = 0; i < 4; i++)
#pragma unroll
        for (int j = 0; j < 4; j++) {
            F[i][j]  = src[(4 * i + j) * HW_];
            A[i][j]  = src[(16 + 4 * i + j) * HW_];
            WT[j][i] = src[(32 + 4 * i + j) * HW_];
        }
    float inten = F[0][0];

    // X = A^-1 F ; M^T = (W^T)^-1 X^T ; normalize by M[0][0]
    float X[4][4], XT[4][4], MT[4][4], M[4][4];
    solve4(A, F, X);
#pragma unroll
    for (int i = 0; i < 4; i++)
#pragma unroll
        for (int j = 0; j < 4; j++) XT[i][j] = X[j][i];
    solve4(WT, XT, MT);
    float nrm = frcp_nr(MT[0][0]);
#pragma unroll
    for (int i = 0; i < 4; i++)
#pragma unroll
        for (int j = 0; j < 4; j++) M[i][j] = MT[j][i] * nrm;

    float* ob = out + (size_t)b * NCH_OUT * HW_ + p;
    float imin = funkey(~mmk[2 * b]), imax = funkey(mmk[2 * b + 1]);
    __builtin_nontemporal_store((inten - imin) * frcp(imax - imin), &ob[0]);
#pragma unroll
    for (int k = 0; k < 16; k++)
        __builtin_nontemporal_store(M[k >> 2][k & 3], &ob[(size_t)(1 + k) * HW_]);

    // ---- charpoly realizability mask (Hermitian form; exact 0.25 scale dropped:
    //      sign tests invariant under exact power-of-2 scaling) ----
    {
        float a0 = M[0][0], b0 = M[0][1], c0 = M[0][2], e0 = M[0][3];
        float a1 = M[1][0], b1 = M[1][1], c1 = M[1][2], e1 = M[1][3];
        float a2 = M[2][0], b2 = M[2][1], c2_ = M[2][2], e2 = M[2][3];
        float a3 = M[3][0], b3 = M[3][1], c3_ = M[3][2], e3 = M[3][3];
        float sa = a0 + a1, da = a0 - a1, sb = b0 + b1, db = b0 - b1;
        float d0 = sa + sb, d1 = sa - sb, d2 = da + db, d3 = da - db;
        float u01r = c0 + c1,  u01i = -(e0 + e1);
        float u23r = c0 - c1,  u23i = -(e0 - e1);
        float u02r = a2 + b2,  u02i = -(a3 + b3);
        float u13r = a2 - b2,  u13i = -(a3 - b3);
        float u03r = c2_ - e3, u03i = -(e2 + c3_);
        float u12r = c2_ + e3, u12i =  (e2 - c3_);

        float n01 = u01r * u01r + u01i * u01i;
        float n02 = u02r * u02r + u02i * u02i;
        float n03 = u03r * u03r + u03i * u03i;
        float n12 = u12r * u12r + u12i * u12i;
        float n13 = u13r * u13r + u13i * u13i;
        float n23 = u23r * u23r + u23i * u23i;

        float q0 = d0 * d0 + n01 + n02 + n03;
        float q1 = d1 * d1 + n01 + n12 + n13;
        float q2 = d2 * d2 + n02 + n12 + n23;
        float q3 = d3 * d3 + n03 + n13 + n23;
        float p2 = q0 + q1 + q2 + q3;

        float w01r = (d0 + d1) * u01r + (u02r * u12r + u02i * u12i) + (u03r * u13r + u03i * u13i);
        float w01i = (d0 + d1) * u01i + (u02i * u12r - u02r * u12i) + (u03i * u13r - u03r * u13i);
        float w02r = (d0 + d2) * u02r + (u01r * u12r - u01i * u12i) + (u03r * u23r + u03i * u23i);
        float w02i = (d0 + d2) * u02i + (u01r * u12i + u01i * u12r) + (u03i * u23r - u03r * u23i);
        float w03r = (d0 + d3) * u03r + (u01r * u13r - u01i * u13i) + (u02r * u23r - u02i * u23i);
        float w03i = (d0 + d3) * u03i + (u01r * u13i + u01i * u13r) + (u02r * u23i + u02i * u23r);
        float w12r = (d1 + d2) * u12r + (u01r * u02r + u01i * u02i) + (u13r * u23r + u13i * u23i);
        float w12i = (d1 + d2) * u12i + (u01r * u02i - u01i * u02r) + (u13i * u23r - u13r * u23i);
        float w13r = (d1 + d3) * u13r + (u01r * u03r + u01i * u03i) + (u12r * u23r - u12i * u23i);
        float w13i = (d1 + d3) * u13i + (u01r * u03i - u01i * u03r) + (u12r * u23i + u12i * u23r);
        float w23r = (d2 + d3) * u23r + (u02r * u03r + u02i * u03i) + (u12r * u13r + u12i * u13i);
        float w23i = (d2 + d3) * u23i + (u02r * u03i - u02i * u03r) + (u12i * u13r - u12r * u13i);

        float p3 = q0 * d0 + q1 * d1 + q2 * d2 + q3 * d3
                 + 2.0f * (w01r * u01r + w01i * u01i + w02r * u02r + w02i * u02i
                         + w03r * u03r + w03i * u03i + w12r * u12r + w12i * u12i
                         + w13r * u13r + w13i * u13i + w23r * u23r + w23i * u23i);
        float p4 = q0 * q0 + q1 * q1 + q2 * q2 + q3 * q3
                 + 2.0f * (w01r * w01r + w01i * w01i + w02r * w02r + w02i * w02i
                         + w03r * w03r + w03i * w03i + w12r * w12r + w12i * w12i
                         + w13r * w13r + w13i * w13i + w23r * w23r + w23i * w23i);

        float tr1 = 4.0f * a0;
        float t2 = tr1 * tr1;
        float c2v = t2 - p2;
        float c3v = tr1 * t2 - 3.0f * tr1 * p2 + 2.0f * p3;
        float c4v = t2 * t2 - 6.0f * t2 * p2 + 3.0f * p2 * p2 + 8.0f * tr1 * p3 - 6.0f * p4;
        bool mask = (tr1 >= 0.0f) && (c2v >= 0.0f) && (c3v >= 0.0f) && (c4v >= 0.0f);

        const float SAFE[4][4] = {{1.0f, 0.02f, 0.01f, 0.005f},
                                  {0.0f, 0.95f, 0.05f, 0.0f},
                                  {0.0f, -0.05f, 0.9f, 0.04f},
                                  {0.0f, 0.0f, -0.04f, 0.85f}};
#pragma unroll
        for (int i = 0; i < 4; i++)
#pragma unroll
            for (int j = 0; j < 4; j++) M[i][j] = mask ? M[i][j] : SAFE[i][j];
    }

    // ---- Lu-Chipman ----
    float D0 = M[0][1], D1 = M[0][2], D2v = M[0][3];
    float d2r = D0 * D0 + D1 * D1 + D2v * D2v;
    float totD = fsqrtf_(d2r + 1e-12f);
    float d2 = fminf(fmaxf(d2r, 0.0f), 1.0f - 1e-6f);
    float d = fsqrtf_(d2 + 1e-12f);
    float sq2 = 1.0f - d2;
    float sq = fsqrtf_(sq2);
    float dinv = frcp(fmaxf(d, 1e-6f));
    float h0 = D0 * dinv, h1 = D1 * dinv, h2 = D2v * dinv;

    float isq2 = frcp_nr(sq2);
    float isq = frcp(sq);
    float cdh = (1.0f - sq) * isq2;
    float MDi[4][4];
    MDi[0][0] = isq2;
    MDi[0][1] = -isq2 * D0; MDi[0][2] = -isq2 * D1; MDi[0][3] = -isq2 * D2v;
    MDi[1][0] = MDi[0][1];  MDi[2][0] = MDi[0][2];  MDi[3][0] = MDi[0][3];
    float Dh[3] = {h0, h1, h2};
#pragma unroll
    for (int i = 0; i < 3; i++)
#pragma unroll
        for (int j = 0; j < 3; j++)
            MDi[1 + i][1 + j] = ((i == j) ? isq : 0.0f) + cdh * Dh[i] * Dh[j];

    float Mp[4][4];
    mul4(M, MDi, Mp);

    float mp3[3][3];
#pragma unroll
    for (int i = 0; i < 3; i++)
#pragma unroll
        for (int j = 0; j < 3; j++) mp3[i][j] = Mp[1 + i][1 + j];
    float mmS[3][3];
#pragma unroll
    for (int i = 0; i < 3; i++)
#pragma unroll
        for (int j = 0; j < 3; j++) {
            float s = 0.0f;
#pragma unroll
            for (int k = 0; k < 3; k++) s += mp3[i][k] * mp3[j][k];
            mmS[i][j] = s;
        }
    float l1, l2, l3;
    eig3_sym(mmS, l1, l2, l3);
    l1 = fmaxf(l1, 1e-12f); l2 = fmaxf(l2, 1e-12f); l3 = fmaxf(l3, 1e-12f);
    float s1 = fsqrtf_(l1), s2 = fsqrtf_(l2), s3 = fsqrtf_(l3);
    float sgn = (det3(mp3) < 0.0f) ? -1.0f : 1.0f;

    float e2s = s1 * s2 + s2 * s3 + s3 * s1 + 1e-6f;
    float e1s = s1 + s2 + s3;
    float e3s = s1 * s2 * s3;
    float A3[3][3], B3[3][3];
#pragma unroll
    for (int i = 0; i < 3; i++)
#pragma unroll
        for (int j = 0; j < 3; j++) {
            A3[i][j] = mmS[i][j] + ((i == j) ? e2s : 0.0f);
            B3[i][j] = e1s * mmS[i][j] + ((i == j) ? e3s : 0.0f);
        }
    float A3i[3][3];
    inv3(A3, A3i);
    float mdel[3][3];
#pragma unroll
    for (int i = 0; i < 3; i++)
#pragma unroll
        for (int j = 0; j < 3; j++) {
            float s = 0.0f;
#pragma unroll
            for (int k = 0; k < 3; k++) s += A3i[i][k] * B3[k][j];
            mdel[i][j] = sgn * s;
        }

    float Pd[3];
#pragma unroll
    for (int i = 0; i < 3; i++)
        Pd[i] = (M[1 + i][0] - (M[1 + i][1] * D0 + M[1 + i][2] * D1 + M[1 + i][3] * D2v)) * isq2;

    float MR0[4];
    const float inv_aeps = 1.0f / (1.0f + 1e-6f);
#pragma unroll
    for (int j = 0; j < 4; j++) MR0[j] = Mp[0][j] * inv_aeps;
    float m3[3][3];
#pragma unroll
    for (int i = 0; i < 3; i++)
#pragma unroll
        for (int j = 0; j < 3; j++) m3[i][j] = mdel[i][j] + ((i == j) ? 1e-6f : 0.0f);
    float m3i[3][3];
    inv3(m3, m3i);
    float MRr[3][4];
#pragma unroll
    for (int i = 0; i < 3; i++)
#pragma unroll
        for (int j = 0; j < 4; j++) {
            float s = 0.0f;
#pragma unroll
            for (int k = 0; k < 3; k++) s += m3i[i][k] * (Mp[1 + k][j] - Pd[k] * MR0[j]);
            MRr[i][j] = s;
        }

    float mR00 = MRr[0][1], mR01 = MRr[0][2], mR02 = MRr[0][3];
    float mR10 = MRr[1][1], mR11 = MRr[1][2], mR12 = MRr[1][3];
    float mR20 = MRr[2][1], mR21 = MRr[2][2];

    float t_lin = fsqrtf_((mR00 + mR11) * (mR00 + mR11) + (mR10 - mR01) * (mR10 - mR01) + 1e-12f) - 1.0f;
    t_lin = fminf(fmaxf(t_lin, -1.0f + 1e-6f), 1.0f - 1e-6f);
    float linR = fast_acos(t_lin) * DEG_;

    float azi = 0.5f * fast_atan2(mR20 - mR02, mR12 - mR21) * DEG_;
    if (azi < 0.0f) azi += 180.0f;

    float totP = 1.0f - fabsf(mdel[0][0] + mdel[1][1] + mdel[2][2]) * (1.0f / 3.0f);

    __builtin_nontemporal_store(linR, &ob[(size_t)17 * HW_]);
    __builtin_nontemporal_store(totP, &ob[(size_t)18 * HW_]);
    __builtin_nontemporal_store(totD, &ob[(size_t)19 * HW_]);
    ob[(size_t)20 * HW_] = azi;   // re-read by circstd: keep cacheable
}

// fused 8x8 SAME rolling circular-std (pad lo=3 hi=4) over out ch20 -> ch21
#define TX_ 32
#define TY_ 8
__global__ __launch_bounds__(256) void circstd_kernel(float* __restrict__ out) {
    int tx0 = blockIdx.x * TX_;
    int ty0 = blockIdx.y * TY_;
    int b = blockIdx.z;
    const float* azi = out + (size_t)b * NCH_OUT * HW_ + (size_t)20 * HW_;

    __shared__ float lc[TY_ + 7][TX_ + 8];
    __shared__ float ls[TY_ + 7][TX_ + 8];
    __shared__ float hc[TY_ + 7][TX_];
    __shared__ float hs[TY_ + 7][TX_];

    for (int i = threadIdx.x; i < (TY_ + 7) * (TX_ + 7); i += 256) {
        int row = i / (TX_ + 7);
        int col = i - row * (TX_ + 7);
        int gy = ty0 - 3 + row;
        int gx = tx0 - 3 + col;
        float c = 0.0f, s = 0.0f;
        if (gy >= 0 && gy < H_ && gx >= 0 && gx < W_) {
            float th = azi[(size_t)gy * W_ + gx] * 0.03490658503988659f;  // pi/90
            __sincosf(th, &s, &c);
        }
        lc[row][col] = c; ls[row][col] = s;
    }
    __syncthreads();

    for (int i = threadIdx.x; i < (TY_ + 7) * TX_; i += 256) {
        int row = i / TX_;
        int col = i - row * TX_;
        float sc = 0.0f, ss = 0.0f;
#pragma unroll
        for (int d = 0; d < 8; d++) { sc += lc[row][col + d]; ss += ls[row][col + d]; }
        hc[row][col] = sc; hs[row][col] = ss;
    }
    __syncthreads();

    int col = threadIdx.x & (TX_ - 1);
    int row = threadIdx.x >> 5;
    float sc = 0.0f, ss = 0.0f;
#pragma unroll
    for (int k = 0; k < 8; k++) { sc += hc[row + k][col]; ss += hs[row + k][col]; }
    int y = ty0 + row, xc = tx0 + col;
    float rows = (float)(min(y + 5, H_) - max(y - 3, 0));
    float cols = (float)(min(xc + 5, W_) - max(xc - 3, 0));
    float R = fsqrtf_(sc * sc + ss * ss + 1e-12f) * frcp(rows * cols);
    R = fminf(fmaxf(R, 1e-7f), 1.0f - 1e-7f);
    float stdv = 0.5f * fsqrtf_(-2.0f * __logf(R)) * DEG_;
    __builtin_nontemporal_store(stdv,
        &out[(size_t)b * NCH_OUT * HW_ + (size_t)21 * HW_ + (size_t)y * W_ + xc]);
}

extern "C" void kernel_launch(void* const* d_in, const int* in_sizes, int n_in,
                              void* d_out, int out_size, void* d_ws, size_t ws_size,
                              hipStream_t stream) {
    const float* x = (const float*)d_in[0];
    float* out = (float*)d_out;
    unsigned int* mmk = (unsigned int*)d_ws;

    hipMemsetAsync(mmk, 0, 4 * sizeof(unsigned int), stream);
    hipLaunchKernelGGL(minmax_kernel, dim3(64), dim3(256), 0, stream, x, mmk);
    hipLaunchKernelGGL(main_kernel, dim3((B_ * HW_ + 255) / 256), dim3(256), 0, stream, x, mmk, out);
    hipLaunchKernelGGL(circstd_kernel, dim3(W_ / TX_, H_ / TY_, B_), dim3(256), 0, stream, out);
}

// Round 6
// 169.763 us; speedup vs baseline: 1.0218x; 1.0218x over previous
//
#include <hip/hip_runtime.h>
#include <math.h>

#define B_ 2
#define H_ 512
#define W_ 512
#define HW_ (H_ * W_)
#define NCH_IN 48
#define NCH_OUT 22
#define DEG_ 57.29577951308232f

__device__ __forceinline__ float frcp(float x)  { return __builtin_amdgcn_rcpf(x); }
// Newton-refined reciprocal: ~2^-28 relative
__device__ __forceinline__ float frcp_nr(float x) {
    float r = __builtin_amdgcn_rcpf(x);
    return r * __builtin_fmaf(-x, r, 2.0f);
}
__device__ __forceinline__ float fsqrtf_(float x){ return __builtin_amdgcn_sqrtf(x); }

__device__ __forceinline__ float fast_acos(float x) {
    float ax = fabsf(x);
    float t = fsqrtf_(fmaxf(1.0f - ax, 0.0f));
    float p = t * (1.5707288f + ax * (-0.2121144f + ax * (0.0742610f + ax * (-0.0187293f))));
    return (x >= 0.0f) ? p : (3.14159265358979f - p);
}

__device__ __forceinline__ float fast_atan2(float y, float x) {
    float ay = fabsf(y), ax = fabsf(x);
    float mx = fmaxf(ax, ay), mn = fminf(ax, ay);
    float a = mn * frcp(fmaxf(mx, 1e-37f));
    float s = a * a;
    float r = a * (0.99997726f + s * (-0.33262347f + s * (0.19354346f +
              s * (-0.11643287f + s * (0.05265332f + s * (-0.01172120f))))));
    if (ay > ax) r = 1.57079632679f - r;
    if (x < 0.0f) r = 3.14159265359f - r;
    return (y < 0.0f) ? -r : r;
}

__device__ __forceinline__ unsigned int fkey(float f) {
    unsigned int u = __float_as_uint(f);
    return (u & 0x80000000u) ? ~u : (u | 0x80000000u);
}
__device__ __forceinline__ float funkey(unsigned int k) {
    return (k & 0x80000000u) ? __uint_as_float(k ^ 0x80000000u) : __uint_as_float(~k);
}

// mm[2b] = max of ~fkey(v) (decodes to min), mm[2b+1] = max of fkey(v); zero-init by memset.
// float4 vector loads: channel 0 of each batch is 1 MB contiguous.
__global__ __launch_bounds__(256) void minmax_kernel(const float* __restrict__ x,
                                                     unsigned int* __restrict__ mm) {
    int b = blockIdx.x >> 5;        // 32 blocks per batch
    int blk = blockIdx.x & 31;
    const float4* src = (const float4*)(x + (size_t)b * NCH_IN * HW_);
    float lo = INFINITY, hi = -INFINITY;
    for (int i = blk * 256 + threadIdx.x; i < HW_ / 4; i += 32 * 256) {
        float4 v = src[i];
        lo = fminf(lo, fminf(fminf(v.x, v.y), fminf(v.z, v.w)));
        hi = fmaxf(hi, fmaxf(fmaxf(v.x, v.y), fmaxf(v.z, v.w)));
    }
    __shared__ float slo[256], shi[256];
    slo[threadIdx.x] = lo; shi[threadIdx.x] = hi;
    __syncthreads();
    for (int s = 128; s > 0; s >>= 1) {
        if (threadIdx.x < s) {
            slo[threadIdx.x] = fminf(slo[threadIdx.x], slo[threadIdx.x + s]);
            shi[threadIdx.x] = fmaxf(shi[threadIdx.x], shi[threadIdx.x + s]);
        }
        __syncthreads();
    }
    if (threadIdx.x == 0) {
        atomicMax(&mm[2 * b], ~fkey(slo[0]));
        atomicMax(&mm[2 * b + 1], fkey(shi[0]));
    }
}

// X = A^-1 * B, Gauss-Jordan with partial pivoting on [A|B] (branchless swaps).
// Dead columns (<k) skipped.
__device__ __forceinline__ void solve4(const float A[4][4], const float Bm[4][4], float X[4][4]) {
    float m[4][8];
#pragma unroll
    for (int i = 0; i < 4; i++) {
#pragma unroll
        for (int j = 0; j < 4; j++) { m[i][j] = A[i][j]; m[i][j + 4] = Bm[i][j]; }
    }
#pragma unroll
    for (int k = 0; k < 4; k++) {
#pragma unroll
        for (int r = k + 1; r < 4; r++) {
            bool sw = fabsf(m[r][k]) > fabsf(m[k][k]);
#pragma unroll
            for (int c = k; c < 8; c++) {
                float a = m[k][c], b = m[r][c];
                m[k][c] = sw ? b : a;
                m[r][c] = sw ? a : b;
            }
        }
        float piv = frcp_nr(m[k][k]);
#pragma unroll
        for (int c = k + 1; c < 8; c++) m[k][c] *= piv;
#pragma unroll
        for (int r = 0; r < 4; r++) {
            if (r == k) continue;
            float f = m[r][k];
#pragma unroll
            for (int c = k + 1; c < 8; c++)
                m[r][c] = __builtin_fmaf(-f, m[k][c], m[r][c]);
        }
    }
#pragma unroll
    for (int i = 0; i < 4; i++)
#pragma unroll
        for (int j = 0; j < 4; j++) X[i][j] = m[i][j + 4];
}

__device__ __forceinline__ void mul4(const float A[4][4], const float B[4][4], float C[4][4]) {
#pragma unroll
    for (int i = 0; i < 4; i++)
#pragma unroll
        for (int j = 0; j < 4; j++) {
            float s = 0.0f;
#pragma unroll
            for (int k = 0; k < 4; k++) s += A[i][k] * B[k][j];
            C[i][j] = s;
        }
}

__device__ __forceinline__ void inv3(const float A[3][3], float out[3][3]) {
    float c00 = A[1][1] * A[2][2] - A[1][2] * A[2][1];
    float c01 = A[1][2] * A[2][0] - A[1][0] * A[2][2];
    float c02 = A[1][0] * A[2][1] - A[1][1] * A[2][0];
    float det = A[0][0] * c00 + A[0][1] * c01 + A[0][2] * c02;
    float id = frcp_nr(det);
    out[0][0] = c00 * id;
    out[0][1] = (A[0][2] * A[2][1] - A[0][1] * A[2][2]) * id;
    out[0][2] = (A[0][1] * A[1][2] - A[0][2] * A[1][1]) * id;
    out[1][0] = c01 * id;
    out[1][1] = (A[0][0] * A[2][2] - A[0][2] * A[2][0]) * id;
    out[1][2] = (A[0][2] * A[1][0] - A[0][0] * A[1][2]) * id;
    out[2][0] = c02 * id;
    out[2][1] = (A[0][1] * A[2][0] - A[0][0] * A[2][1]) * id;
    out[2][2] = (A[0][0] * A[1][1] - A[0][1] * A[1][0]) * id;
}

__device__ __forceinline__ float det3(const float A[3][3]) {
    return A[0][0] * (A[1][1] * A[2][2] - A[1][2] * A[2][1])
         - A[0][1] * (A[1][0] * A[2][2] - A[1][2] * A[2][0])
         + A[0][2] * (A[1][0] * A[2][1] - A[1][1] * A[2][0]);
}

__device__ __forceinline__ void eig3_sym(const float A[3][3], float& l1, float& l2, float& l3) {
    float q = (A[0][0] + A[1][1] + A[2][2]) * (1.0f / 3.0f);
    float a00 = A[0][0] - q, a11 = A[1][1] - q, a22 = A[2][2] - q;
    float off = A[0][1] * A[0][1] + A[0][2] * A[0][2] + A[1][2] * A[1][2];
    float p2 = a00 * a00 + a11 * a11 + a22 * a22 + 2.0f * off;
    float p = fsqrtf_(p2 * (1.0f / 6.0f) + 1e-30f);
    float inv = frcp(p);
    float b00 = a00 * inv, b11 = a11 * inv, b22 = a22 * inv;
    float b01 = A[0][1] * inv, b02 = A[0][2] * inv, b12 = A[1][2] * inv;
    float detB = b00 * (b11 * b22 - b12 * b12)
               - b01 * (b01 * b22 - b12 * b02)
               + b02 * (b01 * b12 - b11 * b02);
    float r = 0.5f * detB;
    r = fminf(fmaxf(r, -1.0f), 1.0f);
    float phi = fast_acos(r) * (1.0f / 3.0f);
    l1 = q + 2.0f * p * __cosf(phi);
    l3 = q + 2.0f * p * __cosf(phi + 2.0943951023931953f);
    l2 = 3.0f * q - l1 - l3;
}

__global__ __launch_bounds__(256) void main_kernel(const float* __restrict__ x,
                                                   const unsigned int* __restrict__ mmk,
                                                   float* __restrict__ out) {
    int idx = blockIdx.x * 256 + threadIdx.x;
    if (idx >= B_ * HW_) return;
    int b = idx / HW_;
    int p = idx - b * HW_;
    const float* src = x + (size_t)b * NCH_IN * HW_ + p;

    // NT loads: zero-reuse 100 MB stream; measured ~2 us faster than cacheable (r3-r5 A/B)
    float F[4][4], A[4][4], WT[4][4];
#pragma unroll
    for (int i = 0; i < 4; i++)
#pragma unroll
        for (int j = 0; j < 4; j++) {
            F[i][j]  = __builtin_nontemporal_load(&src[(4 * i + j) * HW_]);
            A[i][j]  = __builtin_nontemporal_load(&src[(16 + 4 * i + j) * HW_]);
            WT[j][i] = __builtin_nontemporal_load(&src[(32 + 4 * i + j) * HW_]);
        }
    float inten = F[0][0];

    // X = A^-1 F ; M^T = (W^T)^-1 X^T ; normalize by M[0][0]
    float X[4][4], XT[4][4], MT[4][4], M[4][4];
    solve4(A, F, X);
#pragma unroll
    for (int i = 0; i < 4; i++)
#pragma unroll
        for (int j = 0; j < 4; j++) XT[i][j] = X[j][i];
    solve4(WT, XT, MT);
    float nrm = frcp_nr(MT[0][0]);
#pragma unroll
    for (int i = 0; i < 4; i++)
#pragma unroll
        for (int j = 0; j < 4; j++) M[i][j] = MT[j][i] * nrm;

    float* ob = out + (size_t)b * NCH_OUT * HW_ + p;
    float imin = funkey(~mmk[2 * b]), imax = funkey(mmk[2 * b + 1]);
    __builtin_nontemporal_store((inten - imin) * frcp(imax - imin), &ob[0]);
#pragma unroll
    for (int k = 0; k < 16; k++)
        __builtin_nontemporal_store(M[k >> 2][k & 3], &ob[(size_t)(1 + k) * HW_]);

    // ---- charpoly realizability mask (Hermitian form; exact 0.25 scale dropped:
    //      sign tests invariant under exact power-of-2 scaling) ----
    {
        float a0 = M[0][0], b0 = M[0][1], c0 = M[0][2], e0 = M[0][3];
        float a1 = M[1][0], b1 = M[1][1], c1 = M[1][2], e1 = M[1][3];
        float a2 = M[2][0], b2 = M[2][1], c2_ = M[2][2], e2 = M[2][3];
        float a3 = M[3][0], b3 = M[3][1], c3_ = M[3][2], e3 = M[3][3];
        float sa = a0 + a1, da = a0 - a1, sb = b0 + b1, db = b0 - b1;
        float d0 = sa + sb, d1 = sa - sb, d2 = da + db, d3 = da - db;
        float u01r = c0 + c1,  u01i = -(e0 + e1);
        float u23r = c0 - c1,  u23i = -(e0 - e1);
        float u02r = a2 + b2,  u02i = -(a3 + b3);
        float u13r = a2 - b2,  u13i = -(a3 - b3);
        float u03r = c2_ - e3, u03i = -(e2 + c3_);
        float u12r = c2_ + e3, u12i =  (e2 - c3_);

        float n01 = u01r * u01r + u01i * u01i;
        float n02 = u02r * u02r + u02i * u02i;
        float n03 = u03r * u03r + u03i * u03i;
        float n12 = u12r * u12r + u12i * u12i;
        float n13 = u13r * u13r + u13i * u13i;
        float n23 = u23r * u23r + u23i * u23i;

        float q0 = d0 * d0 + n01 + n02 + n03;
        float q1 = d1 * d1 + n01 + n12 + n13;
        float q2 = d2 * d2 + n02 + n12 + n23;
        float q3 = d3 * d3 + n03 + n13 + n23;
        float p2 = q0 + q1 + q2 + q3;

        float w01r = (d0 + d1) * u01r + (u02r * u12r + u02i * u12i) + (u03r * u13r + u03i * u13i);
        float w01i = (d0 + d1) * u01i + (u02i * u12r - u02r * u12i) + (u03i * u13r - u03r * u13i);
        float w02r = (d0 + d2) * u02r + (u01r * u12r - u01i * u12i) + (u03r * u23r + u03i * u23i);
        float w02i = (d0 + d2) * u02i + (u01r * u12i + u01i * u12r) + (u03i * u23r - u03r * u23i);
        float w03r = (d0 + d3) * u03r + (u01r * u13r - u01i * u13i) + (u02r * u23r - u02i * u23i);
        float w03i = (d0 + d3) * u03i + (u01r * u13i + u01i * u13r) + (u02r * u23i + u02i * u23r);
        float w12r = (d1 + d2) * u12r + (u01r * u02r + u01i * u02i) + (u13r * u23r + u13i * u23i);
        float w12i = (d1 + d2) * u12i + (u01r * u02i - u01i * u02r) + (u13i * u23r - u13r * u23i);
        float w13r = (d1 + d3) * u13r + (u01r * u03r + u01i * u03i) + (u12r * u23r - u12i * u23i);
        float w13i = (d1 + d3) * u13i + (u01r * u03i - u01i * u03r) + (u12r * u23i + u12i * u23r);
        float w23r = (d2 + d3) * u23r + (u02r * u03r + u02i * u03i) + (u12r * u13r + u12i * u13i);
        float w23i = (d2 + d3) * u23i + (u02r * u03i - u02i * u03r) + (u12i * u13r - u12r * u13i);

        float p3 = q0 * d0 + q1 * d1 + q2 * d2 + q3 * d3
                 + 2.0f * (w01r * u01r + w01i * u01i + w02r * u02r + w02i * u02i
                         + w03r * u03r + w03i * u03i + w12r * u12r + w12i * u12i
                         + w13r * u13r + w13i * u13i + w23r * u23r + w23i * u23i);
        float p4 = q0 * q0 + q1 * q1 + q2 * q2 + q3 * q3
                 + 2.0f * (w01r * w01r + w01i * w01i + w02r * w02r + w02i * w02i
                         + w03r * w03r + w03i * w03i + w12r * w12r + w12i * w12i
                         + w13r * w13r + w13i * w13i + w23r * w23r + w23i * w23i);

        float tr1 = 4.0f * a0;
        float t2 = tr1 * tr1;
        float c2v = t2 - p2;
        float c3v = tr1 * t2 - 3.0f * tr1 * p2 + 2.0f * p3;
        float c4v = t2 * t2 - 6.0f * t2 * p2 + 3.0f * p2 * p2 + 8.0f * tr1 * p3 - 6.0f * p4;
        bool mask = (tr1 >= 0.0f) && (c2v >= 0.0f) && (c3v >= 0.0f) && (c4v >= 0.0f);

        const float SAFE[4][4] = {{1.0f, 0.02f, 0.01f, 0.005f},
                                  {0.0f, 0.95f, 0.05f, 0.0f},
                                  {0.0f, -0.05f, 0.9f, 0.04f},
                                  {0.0f, 0.0f, -0.04f, 0.85f}};
#pragma unroll
        for (int i = 0; i < 4; i++)
#pragma unroll
            for (int j = 0; j < 4; j++) M[i][j] = mask ? M[i][j] : SAFE[i][j];
    }

    // ---- Lu-Chipman ----
    float D0 = M[0][1], D1 = M[0][2], D2v = M[0][3];
    float d2r = D0 * D0 + D1 * D1 + D2v * D2v;
    float totD = fsqrtf_(d2r + 1e-12f);
    float d2 = fminf(fmaxf(d2r, 0.0f), 1.0f - 1e-6f);
    float d = fsqrtf_(d2 + 1e-12f);
    float sq2 = 1.0f - d2;
    float sq = fsqrtf_(sq2);
    float dinv = frcp(fmaxf(d, 1e-6f));
    float h0 = D0 * dinv, h1 = D1 * dinv, h2 = D2v * dinv;

    float isq2 = frcp_nr(sq2);
    float isq = frcp(sq);
    float cdh = (1.0f - sq) * isq2;
    float MDi[4][4];
    MDi[0][0] = isq2;
    MDi[0][1] = -isq2 * D0; MDi[0][2] = -isq2 * D1; MDi[0][3] = -isq2 * D2v;
    MDi[1][0] = MDi[0][1];  MDi[2][0] = MDi[0][2];  MDi[3][0] = MDi[0][3];
    float Dh[3] = {h0, h1, h2};
#pragma unroll
    for (int i = 0; i < 3; i++)
#pragma unroll
        for (int j = 0; j < 3; j++)
            MDi[1 + i][1 + j] = ((i == j) ? isq : 0.0f) + cdh * Dh[i] * Dh[j];

    float Mp[4][4];
    mul4(M, MDi, Mp);

    float mp3[3][3];
#pragma unroll
    for (int i = 0; i < 3; i++)
#pragma unroll
        for (int j = 0; j < 3; j++) mp3[i][j] = Mp[1 + i][1 + j];
    float mmS[3][3];
#pragma unroll
    for (int i = 0; i < 3; i++)
#pragma unroll
        for (int j = 0; j < 3; j++) {
            float s = 0.0f;
#pragma unroll
            for (int k = 0; k < 3; k++) s += mp3[i][k] * mp3[j][k];
            mmS[i][j] = s;
        }
    float l1, l2, l3;
    eig3_sym(mmS, l1, l2, l3);
    l1 = fmaxf(l1, 1e-12f); l2 = fmaxf(l2, 1e-12f); l3 = fmaxf(l3, 1e-12f);
    float s1 = fsqrtf_(l1), s2 = fsqrtf_(l2), s3 = fsqrtf_(l3);
    float sgn = (det3(mp3) < 0.0f) ? -1.0f : 1.0f;

    float e2s = s1 * s2 + s2 * s3 + s3 * s1 + 1e-6f;
    float e1s = s1 + s2 + s3;
    float e3s = s1 * s2 * s3;
    float A3[3][3], B3[3][3];
#pragma unroll
    for (int i = 0; i < 3; i++)
#pragma unroll
        for (int j = 0; j < 3; j++) {
            A3[i][j] = mmS[i][j] + ((i == j) ? e2s : 0.0f);
            B3[i][j] = e1s * mmS[i][j] + ((i == j) ? e3s : 0.0f);
        }
    float A3i[3][3];
    inv3(A3, A3i);
    float mdel[3][3];
#pragma unroll
    for (int i = 0; i < 3; i++)
#pragma unroll
        for (int j = 0; j < 3; j++) {
            float s = 0.0f;
#pragma unroll
            for (int k = 0; k < 3; k++) s += A3i[i][k] * B3[k][j];
            mdel[i][j] = sgn * s;
        }

    float Pd[3];
#pragma unroll
    for (int i = 0; i < 3; i++)
        Pd[i] = (M[1 + i][0] - (M[1 + i][1] * D0 + M[1 + i][2] * D1 + M[1 + i][3] * D2v)) * isq2;

    float MR0[4];
    const float inv_aeps = 1.0f / (1.0f + 1e-6f);
#pragma unroll
    for (int j = 0; j < 4; j++) MR0[j] = Mp[0][j] * inv_aeps;
    float m3[3][3];
#pragma unroll
    for (int i = 0; i < 3; i++)
#pragma unroll
        for (int j = 0; j < 3; j++) m3[i][j] = mdel[i][j] + ((i == j) ? 1e-6f : 0.0f);
    float m3i[3][3];
    inv3(m3, m3i);
    float MRr[3][4];
#pragma unroll
    for (int i = 0; i < 3; i++)
#pragma unroll
        for (int j = 0; j < 4; j++) {
            float s = 0.0f;
#pragma unroll
            for (int k = 0; k < 3; k++) s += m3i[i][k] * (Mp[1 + k][j] - Pd[k] * MR0[j]);
            MRr[i][j] = s;
        }

    float mR00 = MRr[0][1], mR01 = MRr[0][2], mR02 = MRr[0][3];
    float mR10 = MRr[1][1], mR11 = MRr[1][2], mR12 = MRr[1][3];
    float mR20 = MRr[2][1], mR21 = MRr[2][2];

    float t_lin = fsqrtf_((mR00 + mR11) * (mR00 + mR11) + (mR10 - mR01) * (mR10 - mR01) + 1e-12f) - 1.0f;
    t_lin = fminf(fmaxf(t_lin, -1.0f + 1e-6f), 1.0f - 1e-6f);
    float linR = fast_acos(t_lin) * DEG_;

    float azi = 0.5f * fast_atan2(mR20 - mR02, mR12 - mR21) * DEG_;
    if (azi < 0.0f) azi += 180.0f;

    float totP = 1.0f - fabsf(mdel[0][0] + mdel[1][1] + mdel[2][2]) * (1.0f / 3.0f);

    __builtin_nontemporal_store(linR, &ob[(size_t)17 * HW_]);
    __builtin_nontemporal_store(totP, &ob[(size_t)18 * HW_]);
    __builtin_nontemporal_store(totD, &ob[(size_t)19 * HW_]);
    ob[(size_t)20 * HW_] = azi;   // re-read by circstd: keep cacheable
}

// fused 8x8 SAME rolling circular-std (pad lo=3 hi=4) over out ch20 -> ch21
#define TX_ 32
#define TY_ 8
__global__ __launch_bounds__(256) void circstd_kernel(float* __restrict__ out) {
    int tx0 = blockIdx.x * TX_;
    int ty0 = blockIdx.y * TY_;
    int b = blockIdx.z;
    const float* azi = out + (size_t)b * NCH_OUT * HW_ + (size_t)20 * HW_;

    __shared__ float lc[TY_ + 7][TX_ + 8];
    __shared__ float ls[TY_ + 7][TX_ + 8];
    __shared__ float hc[TY_ + 7][TX_];
    __shared__ float hs[TY_ + 7][TX_];

    for (int i = threadIdx.x; i < (TY_ + 7) * (TX_ + 7); i += 256) {
        int row = i / (TX_ + 7);
        int col = i - row * (TX_ + 7);
        int gy = ty0 - 3 + row;
        int gx = tx0 - 3 + col;
        float c = 0.0f, s = 0.0f;
        if (gy >= 0 && gy < H_ && gx >= 0 && gx < W_) {
            float th = azi[(size_t)gy * W_ + gx] * 0.03490658503988659f;  // pi/90
            __sincosf(th, &s, &c);
        }
        lc[row][col] = c; ls[row][col] = s;
    }
    __syncthreads();

    for (int i = threadIdx.x; i < (TY_ + 7) * TX_; i += 256) {
        int row = i / TX_;
        int col = i - row * TX_;
        float sc = 0.0f, ss = 0.0f;
#pragma unroll
        for (int d = 0; d < 8; d++) { sc += lc[row][col + d]; ss += ls[row][col + d]; }
        hc[row][col] = sc; hs[row][col] = ss;
    }
    __syncthreads();

    int col = threadIdx.x & (TX_ - 1);
    int row = threadIdx.x >> 5;
    float sc = 0.0f, ss = 0.0f;
#pragma unroll
    for (int k = 0; k < 8; k++) { sc += hc[row + k][col]; ss += hs[row + k][col]; }
    int y = ty0 + row, xc = tx0 + col;
    float rows = (float)(min(y + 5, H_) - max(y - 3, 0));
    float cols = (float)(min(xc + 5, W_) - max(xc - 3, 0));
    float R = fsqrtf_(sc * sc + ss * ss + 1e-12f) * frcp(rows * cols);
    R = fminf(fmaxf(R, 1e-7f), 1.0f - 1e-7f);
    float stdv = 0.5f * fsqrtf_(-2.0f * __logf(R)) * DEG_;
    __builtin_nontemporal_store(stdv,
        &out[(size_t)b * NCH_OUT * HW_ + (size_t)21 * HW_ + (size_t)y * W_ + xc]);
}

extern "C" void kernel_launch(void* const* d_in, const int* in_sizes, int n_in,
                              void* d_out, int out_size, void* d_ws, size_t ws_size,
                              hipStream_t stream) {
    const float* x = (const float*)d_in[0];
    float* out = (float*)d_out;
    unsigned int* mmk = (unsigned int*)d_ws;

    hipMemsetAsync(mmk, 0, 4 * sizeof(unsigned int), stream);
    hipLaunchKernelGGL(minmax_kernel, dim3(64), dim3(256), 0, stream, x, mmk);
    hipLaunchKernelGGL(main_kernel, dim3((B_ * HW_ + 255) / 256), dim3(256), 0, stream, x, mmk, out);
    hipLaunchKernelGGL(circstd_kernel, dim3(W_ / TX_, H_ / TY_, B_), dim3(256), 0, stream, out);
}

// Round 7
// 166.213 us; speedup vs baseline: 1.0436x; 1.0214x over previous
//
#include <hip/hip_runtime.h>
#include <math.h>

#define B_ 2
#define H_ 512
#define W_ 512
#define HW_ (H_ * W_)
#define NCH_IN 48
#define NCH_OUT 22
#define DEG_ 57.29577951308232f

typedef float f2 __attribute__((ext_vector_type(2)));

__device__ __forceinline__ float frcp(float x)  { return __builtin_amdgcn_rcpf(x); }
// Newton-refined reciprocal: ~2^-28 relative
__device__ __forceinline__ float frcp_nr(float x) {
    float r = __builtin_amdgcn_rcpf(x);
    return r * __builtin_fmaf(-x, r, 2.0f);
}
__device__ __forceinline__ float fsqrtf_(float x){ return __builtin_amdgcn_sqrtf(x); }

__device__ __forceinline__ float fast_acos(float x) {
    float ax = fabsf(x);
    float t = fsqrtf_(fmaxf(1.0f - ax, 0.0f));
    float p = t * (1.5707288f + ax * (-0.2121144f + ax * (0.0742610f + ax * (-0.0187293f))));
    return (x >= 0.0f) ? p : (3.14159265358979f - p);
}

__device__ __forceinline__ float fast_atan2(float y, float x) {
    float ay = fabsf(y), ax = fabsf(x);
    float mx = fmaxf(ax, ay), mn = fminf(ax, ay);
    float a = mn * frcp(fmaxf(mx, 1e-37f));
    float s = a * a;
    float r = a * (0.99997726f + s * (-0.33262347f + s * (0.19354346f +
              s * (-0.11643287f + s * (0.05265332f + s * (-0.01172120f))))));
    if (ay > ax) r = 1.57079632679f - r;
    if (x < 0.0f) r = 3.14159265359f - r;
    return (y < 0.0f) ? -r : r;
}

__device__ __forceinline__ unsigned int fkey(float f) {
    unsigned int u = __float_as_uint(f);
    return (u & 0x80000000u) ? ~u : (u | 0x80000000u);
}
__device__ __forceinline__ float funkey(unsigned int k) {
    return (k & 0x80000000u) ? __uint_as_float(k ^ 0x80000000u) : __uint_as_float(~k);
}

// mm[2b] = max of ~fkey(v) (decodes to min), mm[2b+1] = max of fkey(v); zero-init by memset.
__global__ __launch_bounds__(256) void minmax_kernel(const float* __restrict__ x,
                                                     unsigned int* __restrict__ mm) {
    int b = blockIdx.x >> 5;        // 32 blocks per batch
    int blk = blockIdx.x & 31;
    const float4* src = (const float4*)(x + (size_t)b * NCH_IN * HW_);
    float lo = INFINITY, hi = -INFINITY;
    for (int i = blk * 256 + threadIdx.x; i < HW_ / 4; i += 32 * 256) {
        float4 v = src[i];
        lo = fminf(lo, fminf(fminf(v.x, v.y), fminf(v.z, v.w)));
        hi = fmaxf(hi, fmaxf(fmaxf(v.x, v.y), fmaxf(v.z, v.w)));
    }
    __shared__ float slo[256], shi[256];
    slo[threadIdx.x] = lo; shi[threadIdx.x] = hi;
    __syncthreads();
    for (int s = 128; s > 0; s >>= 1) {
        if (threadIdx.x < s) {
            slo[threadIdx.x] = fminf(slo[threadIdx.x], slo[threadIdx.x + s]);
            shi[threadIdx.x] = fmaxf(shi[threadIdx.x], shi[threadIdx.x + s]);
        }
        __syncthreads();
    }
    if (threadIdx.x == 0) {
        atomicMax(&mm[2 * b], ~fkey(slo[0]));
        atomicMax(&mm[2 * b + 1], fkey(shi[0]));
    }
}

// Two independent pivoted Gauss-Jordan eliminations on [A|B], interleaved for ILP.
// Dead columns (<k) skipped.
__device__ __forceinline__ void solve4_dual(float m[2][4][8]) {
#pragma unroll
    for (int k = 0; k < 4; k++) {
#pragma unroll
        for (int r = k + 1; r < 4; r++) {
#pragma unroll
            for (int q = 0; q < 2; q++) {
                bool sw = fabsf(m[q][r][k]) > fabsf(m[q][k][k]);
#pragma unroll
                for (int c = k; c < 8; c++) {
                    float a = m[q][k][c], b = m[q][r][c];
                    m[q][k][c] = sw ? b : a;
                    m[q][r][c] = sw ? a : b;
                }
            }
        }
        float piv[2];
#pragma unroll
        for (int q = 0; q < 2; q++) piv[q] = frcp_nr(m[q][k][k]);
#pragma unroll
        for (int c = k + 1; c < 8; c++) {
#pragma unroll
            for (int q = 0; q < 2; q++) m[q][k][c] *= piv[q];
        }
#pragma unroll
        for (int r = 0; r < 4; r++) {
            if (r == k) continue;
#pragma unroll
            for (int q = 0; q < 2; q++) {
                float f = m[q][r][k];
#pragma unroll
                for (int c = k + 1; c < 8; c++)
                    m[q][r][c] = __builtin_fmaf(-f, m[q][k][c], m[q][r][c]);
            }
        }
    }
}

__device__ __forceinline__ void mul4(const float A[4][4], const float B[4][4], float C[4][4]) {
#pragma unroll
    for (int i = 0; i < 4; i++)
#pragma unroll
        for (int j = 0; j < 4; j++) {
            float s = 0.0f;
#pragma unroll
            for (int k = 0; k < 4; k++) s += A[i][k] * B[k][j];
            C[i][j] = s;
        }
}

__device__ __forceinline__ void inv3(const float A[3][3], float out[3][3]) {
    float c00 = A[1][1] * A[2][2] - A[1][2] * A[2][1];
    float c01 = A[1][2] * A[2][0] - A[1][0] * A[2][2];
    float c02 = A[1][0] * A[2][1] - A[1][1] * A[2][0];
    float det = A[0][0] * c00 + A[0][1] * c01 + A[0][2] * c02;
    float id = frcp_nr(det);
    out[0][0] = c00 * id;
    out[0][1] = (A[0][2] * A[2][1] - A[0][1] * A[2][2]) * id;
    out[0][2] = (A[0][1] * A[1][2] - A[0][2] * A[1][1]) * id;
    out[1][0] = c01 * id;
    out[1][1] = (A[0][0] * A[2][2] - A[0][2] * A[2][0]) * id;
    out[1][2] = (A[0][2] * A[1][0] - A[0][0] * A[1][2]) * id;
    out[2][0] = c02 * id;
    out[2][1] = (A[0][1] * A[2][0] - A[0][0] * A[2][1]) * id;
    out[2][2] = (A[0][0] * A[1][1] - A[0][1] * A[1][0]) * id;
}

__device__ __forceinline__ float det3(const float A[3][3]) {
    return A[0][0] * (A[1][1] * A[2][2] - A[1][2] * A[2][1])
         - A[0][1] * (A[1][0] * A[2][2] - A[1][2] * A[2][0])
         + A[0][2] * (A[1][0] * A[2][1] - A[1][1] * A[2][0]);
}

__device__ __forceinline__ void eig3_sym(const float A[3][3], float& l1, float& l2, float& l3) {
    float q = (A[0][0] + A[1][1] + A[2][2]) * (1.0f / 3.0f);
    float a00 = A[0][0] - q, a11 = A[1][1] - q, a22 = A[2][2] - q;
    float off = A[0][1] * A[0][1] + A[0][2] * A[0][2] + A[1][2] * A[1][2];
    float p2 = a00 * a00 + a11 * a11 + a22 * a22 + 2.0f * off;
    float p = fsqrtf_(p2 * (1.0f / 6.0f) + 1e-30f);
    float inv = frcp(p);
    float b00 = a00 * inv, b11 = a11 * inv, b22 = a22 * inv;
    float b01 = A[0][1] * inv, b02 = A[0][2] * inv, b12 = A[1][2] * inv;
    float detB = b00 * (b11 * b22 - b12 * b12)
               - b01 * (b01 * b22 - b12 * b02)
               + b02 * (b01 * b12 - b11 * b02);
    float r = 0.5f * detB;
    r = fminf(fmaxf(r, -1.0f), 1.0f);
    float phi = fast_acos(r) * (1.0f / 3.0f);
    l1 = q + 2.0f * p * __cosf(phi);
    l3 = q + 2.0f * p * __cosf(phi + 2.0943951023931953f);
    l2 = 3.0f * q - l1 - l3;
}

// charpoly mask -> Lu-Chipman -> polarimetry for one pixel; returns 4 scalars.
__device__ __forceinline__ void pixel_tail(float M[4][4], float& linR_o, float& totP_o,
                                           float& totD_o, float& azi_o) {
    // ---- charpoly realizability mask (Hermitian form; exact 0.25 scale dropped) ----
    {
        float a0 = M[0][0], b0 = M[0][1], c0 = M[0][2], e0 = M[0][3];
        float a1 = M[1][0], b1 = M[1][1], c1 = M[1][2], e1 = M[1][3];
        float a2 = M[2][0], b2 = M[2][1], c2_ = M[2][2], e2 = M[2][3];
        float a3 = M[3][0], b3 = M[3][1], c3_ = M[3][2], e3 = M[3][3];
        float sa = a0 + a1, da = a0 - a1, sb = b0 + b1, db = b0 - b1;
        float d0 = sa + sb, d1 = sa - sb, d2 = da + db, d3 = da - db;
        float u01r = c0 + c1,  u01i = -(e0 + e1);
        float u23r = c0 - c1,  u23i = -(e0 - e1);
        float u02r = a2 + b2,  u02i = -(a3 + b3);
        float u13r = a2 - b2,  u13i = -(a3 - b3);
        float u03r = c2_ - e3, u03i = -(e2 + c3_);
        float u12r = c2_ + e3, u12i =  (e2 - c3_);

        float n01 = u01r * u01r + u01i * u01i;
        float n02 = u02r * u02r + u02i * u02i;
        float n03 = u03r * u03r + u03i * u03i;
        float n12 = u12r * u12r + u12i * u12i;
        float n13 = u13r * u13r + u13i * u13i;
        float n23 = u23r * u23r + u23i * u23i;

        float q0 = d0 * d0 + n01 + n02 + n03;
        float q1 = d1 * d1 + n01 + n12 + n13;
        float q2 = d2 * d2 + n02 + n12 + n23;
        float q3 = d3 * d3 + n03 + n13 + n23;
        float p2 = q0 + q1 + q2 + q3;

        float w01r = (d0 + d1) * u01r + (u02r * u12r + u02i * u12i) + (u03r * u13r + u03i * u13i);
        float w01i = (d0 + d1) * u01i + (u02i * u12r - u02r * u12i) + (u03i * u13r - u03r * u13i);
        float w02r = (d0 + d2) * u02r + (u01r * u12r - u01i * u12i) + (u03r * u23r + u03i * u23i);
        float w02i = (d0 + d2) * u02i + (u01r * u12i + u01i * u12r) + (u03i * u23r - u03r * u23i);
        float w03r = (d0 + d3) * u03r + (u01r * u13r - u01i * u13i) + (u02r * u23r - u02i * u23i);
        float w03i = (d0 + d3) * u03i + (u01r * u13i + u01i * u13r) + (u02r * u23i + u02i * u23r);
        float w12r = (d1 + d2) * u12r + (u01r * u02r + u01i * u02i) + (u13r * u23r + u13i * u23i);
        float w12i = (d1 + d2) * u12i + (u01r * u02i - u01i * u02r) + (u13i * u23r - u13r * u23i);
        float w13r = (d1 + d3) * u13r + (u01r * u03r + u01i * u03i) + (u12r * u23r - u12i * u23i);
        float w13i = (d1 + d3) * u13i + (u01r * u03i - u01i * u03r) + (u12r * u23i + u12i * u23r);
        float w23r = (d2 + d3) * u23r + (u02r * u03r + u02i * u03i) + (u12r * u13r + u12i * u13i);
        float w23i = (d2 + d3) * u23i + (u02r * u03i - u02i * u03r) + (u12i * u13r - u12r * u13i);

        float p3 = q0 * d0 + q1 * d1 + q2 * d2 + q3 * d3
                 + 2.0f * (w01r * u01r + w01i * u01i + w02r * u02r + w02i * u02i
                         + w03r * u03r + w03i * u03i + w12r * u12r + w12i * u12i
                         + w13r * u13r + w13i * u13i + w23r * u23r + w23i * u23i);
        float p4 = q0 * q0 + q1 * q1 + q2 * q2 + q3 * q3
                 + 2.0f * (w01r * w01r + w01i * w01i + w02r * w02r + w02i * w02i
                         + w03r * w03r + w03i * w03i + w12r * w12r + w12i * w12i
                         + w13r * w13r + w13i * w13i + w23r * w23r + w23i * w23i);

        float tr1 = 4.0f * a0;
        float t2 = tr1 * tr1;
        float c2v = t2 - p2;
        float c3v = tr1 * t2 - 3.0f * tr1 * p2 + 2.0f * p3;
        float c4v = t2 * t2 - 6.0f * t2 * p2 + 3.0f * p2 * p2 + 8.0f * tr1 * p3 - 6.0f * p4;
        bool mask = (tr1 >= 0.0f) && (c2v >= 0.0f) && (c3v >= 0.0f) && (c4v >= 0.0f);

        const float SAFE[4][4] = {{1.0f, 0.02f, 0.01f, 0.005f},
                                  {0.0f, 0.95f, 0.05f, 0.0f},
                                  {0.0f, -0.05f, 0.9f, 0.04f},
                                  {0.0f, 0.0f, -0.04f, 0.85f}};
#pragma unroll
        for (int i = 0; i < 4; i++)
#pragma unroll
            for (int j = 0; j < 4; j++) M[i][j] = mask ? M[i][j] : SAFE[i][j];
    }

    // ---- Lu-Chipman ----
    float D0 = M[0][1], D1 = M[0][2], D2v = M[0][3];
    float d2r = D0 * D0 + D1 * D1 + D2v * D2v;
    float totD = fsqrtf_(d2r + 1e-12f);
    float d2 = fminf(fmaxf(d2r, 0.0f), 1.0f - 1e-6f);
    float d = fsqrtf_(d2 + 1e-12f);
    float sq2 = 1.0f - d2;
    float sq = fsqrtf_(sq2);
    float dinv = frcp(fmaxf(d, 1e-6f));
    float h0 = D0 * dinv, h1 = D1 * dinv, h2 = D2v * dinv;

    float isq2 = frcp_nr(sq2);
    float isq = frcp(sq);
    float cdh = (1.0f - sq) * isq2;
    float MDi[4][4];
    MDi[0][0] = isq2;
    MDi[0][1] = -isq2 * D0; MDi[0][2] = -isq2 * D1; MDi[0][3] = -isq2 * D2v;
    MDi[1][0] = MDi[0][1];  MDi[2][0] = MDi[0][2];  MDi[3][0] = MDi[0][3];
    float Dh[3] = {h0, h1, h2};
#pragma unroll
    for (int i = 0; i < 3; i++)
#pragma unroll
        for (int j = 0; j < 3; j++)
            MDi[1 + i][1 + j] = ((i == j) ? isq : 0.0f) + cdh * Dh[i] * Dh[j];

    float Mp[4][4];
    mul4(M, MDi, Mp);

    float mp3[3][3];
#pragma unroll
    for (int i = 0; i < 3; i++)
#pragma unroll
        for (int j = 0; j < 3; j++) mp3[i][j] = Mp[1 + i][1 + j];
    float mmS[3][3];
#pragma unroll
    for (int i = 0; i < 3; i++)
#pragma unroll
        for (int j = 0; j < 3; j++) {
            float s = 0.0f;
#pragma unroll
            for (int k = 0; k < 3; k++) s += mp3[i][k] * mp3[j][k];
            mmS[i][j] = s;
        }
    float l1, l2, l3;
    eig3_sym(mmS, l1, l2, l3);
    l1 = fmaxf(l1, 1e-12f); l2 = fmaxf(l2, 1e-12f); l3 = fmaxf(l3, 1e-12f);
    float s1 = fsqrtf_(l1), s2 = fsqrtf_(l2), s3 = fsqrtf_(l3);
    float sgn = (det3(mp3) < 0.0f) ? -1.0f : 1.0f;

    float e2s = s1 * s2 + s2 * s3 + s3 * s1 + 1e-6f;
    float e1s = s1 + s2 + s3;
    float e3s = s1 * s2 * s3;
    float A3[3][3], B3[3][3];
#pragma unroll
    for (int i = 0; i < 3; i++)
#pragma unroll
        for (int j = 0; j < 3; j++) {
            A3[i][j] = mmS[i][j] + ((i == j) ? e2s : 0.0f);
            B3[i][j] = e1s * mmS[i][j] + ((i == j) ? e3s : 0.0f);
        }
    float A3i[3][3];
    inv3(A3, A3i);
    float mdel[3][3];
#pragma unroll
    for (int i = 0; i < 3; i++)
#pragma unroll
        for (int j = 0; j < 3; j++) {
            float s = 0.0f;
#pragma unroll
            for (int k = 0; k < 3; k++) s += A3i[i][k] * B3[k][j];
            mdel[i][j] = sgn * s;
        }

    float Pd[3];
#pragma unroll
    for (int i = 0; i < 3; i++)
        Pd[i] = (M[1 + i][0] - (M[1 + i][1] * D0 + M[1 + i][2] * D1 + M[1 + i][3] * D2v)) * isq2;

    float MR0[4];
    const float inv_aeps = 1.0f / (1.0f + 1e-6f);
#pragma unroll
    for (int j = 0; j < 4; j++) MR0[j] = Mp[0][j] * inv_aeps;
    float m3[3][3];
#pragma unroll
    for (int i = 0; i < 3; i++)
#pragma unroll
        for (int j = 0; j < 3; j++) m3[i][j] = mdel[i][j] + ((i == j) ? 1e-6f : 0.0f);
    float m3i[3][3];
    inv3(m3, m3i);
    float MRr[3][4];
#pragma unroll
    for (int i = 0; i < 3; i++)
#pragma unroll
        for (int j = 0; j < 4; j++) {
            float s = 0.0f;
#pragma unroll
            for (int k = 0; k < 3; k++) s += m3i[i][k] * (Mp[1 + k][j] - Pd[k] * MR0[j]);
            MRr[i][j] = s;
        }

    float mR00 = MRr[0][1], mR01 = MRr[0][2], mR02 = MRr[0][3];
    float mR10 = MRr[1][1], mR11 = MRr[1][2], mR12 = MRr[1][3];
    float mR20 = MRr[2][1], mR21 = MRr[2][2];

    float t_lin = fsqrtf_((mR00 + mR11) * (mR00 + mR11) + (mR10 - mR01) * (mR10 - mR01) + 1e-12f) - 1.0f;
    t_lin = fminf(fmaxf(t_lin, -1.0f + 1e-6f), 1.0f - 1e-6f);
    float linR = fast_acos(t_lin) * DEG_;

    float azi = 0.5f * fast_atan2(mR20 - mR02, mR12 - mR21) * DEG_;
    if (azi < 0.0f) azi += 180.0f;

    float totP = 1.0f - fabsf(mdel[0][0] + mdel[1][1] + mdel[2][2]) * (1.0f / 3.0f);

    linR_o = linR; totP_o = totP; totD_o = totD; azi_o = azi;
}

// One thread = two ADJACENT pixels (2t, 2t+1) of the same batch: all global
// loads become dwordx2 (48 -> 24 per pixel-equivalent) and all stores become
// fully-coalesced dwordx2. Solves dual-interleaved; tails sequential.
__global__ __launch_bounds__(256) void main_kernel(const float* __restrict__ x,
                                                   const unsigned int* __restrict__ mmk,
                                                   float* __restrict__ out) {
    int tid = blockIdx.x * 256 + threadIdx.x;       // 0 .. B_*HW_/2 - 1
    int b = tid / (HW_ / 2);
    int pp = tid - b * (HW_ / 2);
    int p = pp * 2;
    const float* src = x + (size_t)b * NCH_IN * HW_ + p;

    float m[2][4][8];       // [pixel][row][A|F]
    float Wv[2][4][4];      // W^T per pixel
#pragma unroll
    for (int i = 0; i < 4; i++)
#pragma unroll
        for (int j = 0; j < 4; j++) {
            f2 f = __builtin_nontemporal_load((const f2*)&src[(size_t)(4 * i + j) * HW_]);
            f2 a = __builtin_nontemporal_load((const f2*)&src[(size_t)(16 + 4 * i + j) * HW_]);
            f2 w = __builtin_nontemporal_load((const f2*)&src[(size_t)(32 + 4 * i + j) * HW_]);
            m[0][i][4 + j] = f.x; m[1][i][4 + j] = f.y;
            m[0][i][j]     = a.x; m[1][i][j]     = a.y;
            Wv[0][j][i]    = w.x; Wv[1][j][i]    = w.y;
        }
    float inten0 = m[0][0][4], inten1 = m[1][0][4];

    solve4_dual(m);   // cols 4..7 = X = A^-1 F

    float m2[2][4][8];
#pragma unroll
    for (int q = 0; q < 2; q++)
#pragma unroll
        for (int i = 0; i < 4; i++)
#pragma unroll
            for (int j = 0; j < 4; j++) {
                m2[q][i][j]     = Wv[q][i][j];
                m2[q][i][4 + j] = m[q][j][4 + i];   // X^T
            }
    solve4_dual(m2);  // cols 4..7 = M^T

    float M[2][4][4];
#pragma unroll
    for (int q = 0; q < 2; q++) {
        float nrm = frcp_nr(m2[q][0][4]);
#pragma unroll
        for (int i = 0; i < 4; i++)
#pragma unroll
            for (int j = 0; j < 4; j++) M[q][i][j] = m2[q][j][4 + i] * nrm;
    }

    float* ob = out + (size_t)b * NCH_OUT * HW_ + p;
    float imin = funkey(~mmk[2 * b]), imax = funkey(mmk[2 * b + 1]);
    float iscale = frcp(imax - imin);
    {
        f2 v; v.x = (inten0 - imin) * iscale; v.y = (inten1 - imin) * iscale;
        __builtin_nontemporal_store(v, (f2*)&ob[0]);
    }
#pragma unroll
    for (int k = 0; k < 16; k++) {
        f2 v; v.x = M[0][k >> 2][k & 3]; v.y = M[1][k >> 2][k & 3];
        __builtin_nontemporal_store(v, (f2*)&ob[(size_t)(1 + k) * HW_]);
    }

    float linR[2], totP[2], totD[2], azi[2];
#pragma unroll
    for (int q = 0; q < 2; q++)
        pixel_tail(M[q], linR[q], totP[q], totD[q], azi[q]);

    f2 v;
    v.x = linR[0]; v.y = linR[1]; __builtin_nontemporal_store(v, (f2*)&ob[(size_t)17 * HW_]);
    v.x = totP[0]; v.y = totP[1]; __builtin_nontemporal_store(v, (f2*)&ob[(size_t)18 * HW_]);
    v.x = totD[0]; v.y = totD[1]; __builtin_nontemporal_store(v, (f2*)&ob[(size_t)19 * HW_]);
    v.x = azi[0];  v.y = azi[1];  *(f2*)&ob[(size_t)20 * HW_] = v;   // re-read by circstd
}

// fused 8x8 SAME rolling circular-std (pad lo=3 hi=4) over out ch20 -> ch21
#define TX_ 32
#define TY_ 8
__global__ __launch_bounds__(256) void circstd_kernel(float* __restrict__ out) {
    int tx0 = blockIdx.x * TX_;
    int ty0 = blockIdx.y * TY_;
    int b = blockIdx.z;
    const float* azi = out + (size_t)b * NCH_OUT * HW_ + (size_t)20 * HW_;

    __shared__ float lc[TY_ + 7][TX_ + 8];
    __shared__ float ls[TY_ + 7][TX_ + 8];
    __shared__ float hc[TY_ + 7][TX_];
    __shared__ float hs[TY_ + 7][TX_];

    for (int i = threadIdx.x; i < (TY_ + 7) * (TX_ + 7); i += 256) {
        int row = i / (TX_ + 7);
        int col = i - row * (TX_ + 7);
        int gy = ty0 - 3 + row;
        int gx = tx0 - 3 + col;
        float c = 0.0f, s = 0.0f;
        if (gy >= 0 && gy < H_ && gx >= 0 && gx < W_) {
            float th = azi[(size_t)gy * W_ + gx] * 0.03490658503988659f;  // pi/90
            __sincosf(th, &s, &c);
        }
        lc[row][col] = c; ls[row][col] = s;
    }
    __syncthreads();

    for (int i = threadIdx.x; i < (TY_ + 7) * TX_; i += 256) {
        int row = i / TX_;
        int col = i - row * TX_;
        float sc = 0.0f, ss = 0.0f;
#pragma unroll
        for (int d = 0; d < 8; d++) { sc += lc[row][col + d]; ss += ls[row][col + d]; }
        hc[row][col] = sc; hs[row][col] = ss;
    }
    __syncthreads();

    int col = threadIdx.x & (TX_ - 1);
    int row = threadIdx.x >> 5;
    float sc = 0.0f, ss = 0.0f;
#pragma unroll
    for (int k = 0; k < 8; k++) { sc += hc[row + k][col]; ss += hs[row + k][col]; }
    int y = ty0 + row, xc = tx0 + col;
    float rows = (float)(min(y + 5, H_) - max(y - 3, 0));
    float cols = (float)(min(xc + 5, W_) - max(xc - 3, 0));
    float R = fsqrtf_(sc * sc + ss * ss + 1e-12f) * frcp(rows * cols);
    R = fminf(fmaxf(R, 1e-7f), 1.0f - 1e-7f);
    float stdv = 0.5f * fsqrtf_(-2.0f * __logf(R)) * DEG_;
    __builtin_nontemporal_store(stdv,
        &out[(size_t)b * NCH_OUT * HW_ + (size_t)21 * HW_ + (size_t)y * W_ + xc]);
}

extern "C" void kernel_launch(void* const* d_in, const int* in_sizes, int n_in,
                              void* d_out, int out_size, void* d_ws, size_t ws_size,
                              hipStream_t stream) {
    const float* x = (const float*)d_in[0];
    float* out = (float*)d_out;
    unsigned int* mmk = (unsigned int*)d_ws;

    hipMemsetAsync(mmk, 0, 4 * sizeof(unsigned int), stream);
    hipLaunchKernelGGL(minmax_kernel, dim3(64), dim3(256), 0, stream, x, mmk);
    hipLaunchKernelGGL(main_kernel, dim3(B_ * HW_ / 2 / 256), dim3(256), 0, stream, x, mmk, out);
    hipLaunchKernelGGL(circstd_kernel, dim3(W_ / TX_, H_ / TY_, B_), dim3(256), 0, stream, out);
}

// Round 8
// 165.823 us; speedup vs baseline: 1.0461x; 1.0023x over previous
//
#include <hip/hip_runtime.h>
#include <math.h>

#define B_ 2
#define H_ 512
#define W_ 512
#define HW_ (H_ * W_)
#define NCH_IN 48
#define NCH_OUT 22
#define DEG_ 57.29577951308232f

typedef float f2 __attribute__((ext_vector_type(2)));

__device__ __forceinline__ float frcp(float x)  { return __builtin_amdgcn_rcpf(x); }
// Newton-refined reciprocal: ~2^-28 relative
__device__ __forceinline__ float frcp_nr(float x) {
    float r = __builtin_amdgcn_rcpf(x);
    return r * __builtin_fmaf(-x, r, 2.0f);
}
__device__ __forceinline__ float fsqrtf_(float x){ return __builtin_amdgcn_sqrtf(x); }

__device__ __forceinline__ float fast_acos(float x) {
    float ax = fabsf(x);
    float t = fsqrtf_(fmaxf(1.0f - ax, 0.0f));
    float p = t * (1.5707288f + ax * (-0.2121144f + ax * (0.0742610f + ax * (-0.0187293f))));
    return (x >= 0.0f) ? p : (3.14159265358979f - p);
}

__device__ __forceinline__ float fast_atan2(float y, float x) {
    float ay = fabsf(y), ax = fabsf(x);
    float mx = fmaxf(ax, ay), mn = fminf(ax, ay);
    float a = mn * frcp(fmaxf(mx, 1e-37f));
    float s = a * a;
    float r = a * (0.99997726f + s * (-0.33262347f + s * (0.19354346f +
              s * (-0.11643287f + s * (0.05265332f + s * (-0.01172120f))))));
    if (ay > ax) r = 1.57079632679f - r;
    if (x < 0.0f) r = 3.14159265359f - r;
    return (y < 0.0f) ? -r : r;
}

__device__ __forceinline__ unsigned int fkey(float f) {
    unsigned int u = __float_as_uint(f);
    return (u & 0x80000000u) ? ~u : (u | 0x80000000u);
}
__device__ __forceinline__ float funkey(unsigned int k) {
    return (k & 0x80000000u) ? __uint_as_float(k ^ 0x80000000u) : __uint_as_float(~k);
}

// mm[2b] = max of ~fkey(v) (decodes to min), mm[2b+1] = max of fkey(v); zero-init by memset.
__global__ __launch_bounds__(256) void minmax_kernel(const float* __restrict__ x,
                                                     unsigned int* __restrict__ mm) {
    int b = blockIdx.x >> 5;        // 32 blocks per batch
    int blk = blockIdx.x & 31;
    const float4* src = (const float4*)(x + (size_t)b * NCH_IN * HW_);
    float lo = INFINITY, hi = -INFINITY;
    for (int i = blk * 256 + threadIdx.x; i < HW_ / 4; i += 32 * 256) {
        float4 v = src[i];
        lo = fminf(lo, fminf(fminf(v.x, v.y), fminf(v.z, v.w)));
        hi = fmaxf(hi, fmaxf(fmaxf(v.x, v.y), fmaxf(v.z, v.w)));
    }
    __shared__ float slo[256], shi[256];
    slo[threadIdx.x] = lo; shi[threadIdx.x] = hi;
    __syncthreads();
    for (int s = 128; s > 0; s >>= 1) {
        if (threadIdx.x < s) {
            slo[threadIdx.x] = fminf(slo[threadIdx.x], slo[threadIdx.x + s]);
            shi[threadIdx.x] = fmaxf(shi[threadIdx.x], shi[threadIdx.x + s]);
        }
        __syncthreads();
    }
    if (threadIdx.x == 0) {
        atomicMax(&mm[2 * b], ~fkey(slo[0]));
        atomicMax(&mm[2 * b + 1], fkey(shi[0]));
    }
}

// Two independent pivoted Gauss-Jordan eliminations on [A|B], interleaved for ILP.
// Dead columns (<k) skipped.
__device__ __forceinline__ void solve4_dual(float m[2][4][8]) {
#pragma unroll
    for (int k = 0; k < 4; k++) {
#pragma unroll
        for (int r = k + 1; r < 4; r++) {
#pragma unroll
            for (int q = 0; q < 2; q++) {
                bool sw = fabsf(m[q][r][k]) > fabsf(m[q][k][k]);
#pragma unroll
                for (int c = k; c < 8; c++) {
                    float a = m[q][k][c], b = m[q][r][c];
                    m[q][k][c] = sw ? b : a;
                    m[q][r][c] = sw ? a : b;
                }
            }
        }
        float piv[2];
#pragma unroll
        for (int q = 0; q < 2; q++) piv[q] = frcp_nr(m[q][k][k]);
#pragma unroll
        for (int c = k + 1; c < 8; c++) {
#pragma unroll
            for (int q = 0; q < 2; q++) m[q][k][c] *= piv[q];
        }
#pragma unroll
        for (int r = 0; r < 4; r++) {
            if (r == k) continue;
#pragma unroll
            for (int q = 0; q < 2; q++) {
                float f = m[q][r][k];
#pragma unroll
                for (int c = k + 1; c < 8; c++)
                    m[q][r][c] = __builtin_fmaf(-f, m[q][k][c], m[q][r][c]);
            }
        }
    }
}

__device__ __forceinline__ void mul4(const float A[4][4], const float B[4][4], float C[4][4]) {
#pragma unroll
    for (int i = 0; i < 4; i++)
#pragma unroll
        for (int j = 0; j < 4; j++) {
            float s = 0.0f;
#pragma unroll
            for (int k = 0; k < 4; k++) s += A[i][k] * B[k][j];
            C[i][j] = s;
        }
}

__device__ __forceinline__ void inv3(const float A[3][3], float out[3][3]) {
    float c00 = A[1][1] * A[2][2] - A[1][2] * A[2][1];
    float c01 = A[1][2] * A[2][0] - A[1][0] * A[2][2];
    float c02 = A[1][0] * A[2][1] - A[1][1] * A[2][0];
    float det = A[0][0] * c00 + A[0][1] * c01 + A[0][2] * c02;
    float id = frcp_nr(det);
    out[0][0] = c00 * id;
    out[0][1] = (A[0][2] * A[2][1] - A[0][1] * A[2][2]) * id;
    out[0][2] = (A[0][1] * A[1][2] - A[0][2] * A[1][1]) * id;
    out[1][0] = c01 * id;
    out[1][1] = (A[0][0] * A[2][2] - A[0][2] * A[2][0]) * id;
    out[1][2] = (A[0][2] * A[1][0] - A[0][0] * A[1][2]) * id;
    out[2][0] = c02 * id;
    out[2][1] = (A[0][1] * A[2][0] - A[0][0] * A[2][1]) * id;
    out[2][2] = (A[0][0] * A[1][1] - A[0][1] * A[1][0]) * id;
}

__device__ __forceinline__ float det3(const float A[3][3]) {
    return A[0][0] * (A[1][1] * A[2][2] - A[1][2] * A[2][1])
         - A[0][1] * (A[1][0] * A[2][2] - A[1][2] * A[2][0])
         + A[0][2] * (A[1][0] * A[2][1] - A[1][1] * A[2][0]);
}

__device__ __forceinline__ void eig3_sym(const float A[3][3], float& l1, float& l2, float& l3) {
    float q = (A[0][0] + A[1][1] + A[2][2]) * (1.0f / 3.0f);
    float a00 = A[0][0] - q, a11 = A[1][1] - q, a22 = A[2][2] - q;
    float off = A[0][1] * A[0][1] + A[0][2] * A[0][2] + A[1][2] * A[1][2];
    float p2 = a00 * a00 + a11 * a11 + a22 * a22 + 2.0f * off;
    float p = fsqrtf_(p2 * (1.0f / 6.0f) + 1e-30f);
    float inv = frcp(p);
    float b00 = a00 * inv, b11 = a11 * inv, b22 = a22 * inv;
    float b01 = A[0][1] * inv, b02 = A[0][2] * inv, b12 = A[1][2] * inv;
    float detB = b00 * (b11 * b22 - b12 * b12)
               - b01 * (b01 * b22 - b12 * b02)
               + b02 * (b01 * b12 - b11 * b02);
    float r = 0.5f * detB;
    r = fminf(fmaxf(r, -1.0f), 1.0f);
    float phi = fast_acos(r) * (1.0f / 3.0f);
    l1 = q + 2.0f * p * __cosf(phi);
    l3 = q + 2.0f * p * __cosf(phi + 2.0943951023931953f);
    l2 = 3.0f * q - l1 - l3;
}

// charpoly mask -> Lu-Chipman -> polarimetry for one pixel; returns 4 scalars.
__device__ __forceinline__ void pixel_tail(float M[4][4], float& linR_o, float& totP_o,
                                           float& totD_o, float& azi_o) {
    // ---- charpoly realizability mask (Hermitian form; exact 0.25 scale dropped) ----
    {
        float a0 = M[0][0], b0 = M[0][1], c0 = M[0][2], e0 = M[0][3];
        float a1 = M[1][0], b1 = M[1][1], c1 = M[1][2], e1 = M[1][3];
        float a2 = M[2][0], b2 = M[2][1], c2_ = M[2][2], e2 = M[2][3];
        float a3 = M[3][0], b3 = M[3][1], c3_ = M[3][2], e3 = M[3][3];
        float sa = a0 + a1, da = a0 - a1, sb = b0 + b1, db = b0 - b1;
        float d0 = sa + sb, d1 = sa - sb, d2 = da + db, d3 = da - db;
        float u01r = c0 + c1,  u01i = -(e0 + e1);
        float u23r = c0 - c1,  u23i = -(e0 - e1);
        float u02r = a2 + b2,  u02i = -(a3 + b3);
        float u13r = a2 - b2,  u13i = -(a3 - b3);
        float u03r = c2_ - e3, u03i = -(e2 + c3_);
        float u12r = c2_ + e3, u12i =  (e2 - c3_);

        float n01 = u01r * u01r + u01i * u01i;
        float n02 = u02r * u02r + u02i * u02i;
        float n03 = u03r * u03r + u03i * u03i;
        float n12 = u12r * u12r + u12i * u12i;
        float n13 = u13r * u13r + u13i * u13i;
        float n23 = u23r * u23r + u23i * u23i;

        float q0 = d0 * d0 + n01 + n02 + n03;
        float q1 = d1 * d1 + n01 + n12 + n13;
        float q2 = d2 * d2 + n02 + n12 + n23;
        float q3 = d3 * d3 + n03 + n13 + n23;
        float p2 = q0 + q1 + q2 + q3;

        float w01r = (d0 + d1) * u01r + (u02r * u12r + u02i * u12i) + (u03r * u13r + u03i * u13i);
        float w01i = (d0 + d1) * u01i + (u02i * u12r - u02r * u12i) + (u03i * u13r - u03r * u13i);
        float w02r = (d0 + d2) * u02r + (u01r * u12r - u01i * u12i) + (u03r * u23r + u03i * u23i);
        float w02i = (d0 + d2) * u02i + (u01r * u12i + u01i * u12r) + (u03i * u23r - u03r * u23i);
        float w03r = (d0 + d3) * u03r + (u01r * u13r - u01i * u13i) + (u02r * u23r - u02i * u23i);
        float w03i = (d0 + d3) * u03i + (u01r * u13i + u01i * u13r) + (u02r * u23i + u02i * u23r);
        float w12r = (d1 + d2) * u12r + (u01r * u02r + u01i * u02i) + (u13r * u23r + u13i * u23i);
        float w12i = (d1 + d2) * u12i + (u01r * u02i - u01i * u02r) + (u13i * u23r - u13r * u23i);
        float w13r = (d1 + d3) * u13r + (u01r * u03r + u01i * u03i) + (u12r * u23r - u12i * u23i);
        float w13i = (d1 + d3) * u13i + (u01r * u03i - u01i * u03r) + (u12r * u23i + u12i * u23r);
        float w23r = (d2 + d3) * u23r + (u02r * u03r + u02i * u03i) + (u12r * u13r + u12i * u13i);
        float w23i = (d2 + d3) * u23i + (u02r * u03i - u02i * u03r) + (u12i * u13r - u12r * u13i);

        float p3 = q0 * d0 + q1 * d1 + q2 * d2 + q3 * d3
                 + 2.0f * (w01r * u01r + w01i * u01i + w02r * u02r + w02i * u02i
                         + w03r * u03r + w03i * u03i + w12r * u12r + w12i * u12i
                         + w13r * u13r + w13i * u13i + w23r * u23r + w23i * u23i);
        float p4 = q0 * q0 + q1 * q1 + q2 * q2 + q3 * q3
                 + 2.0f * (w01r * w01r + w01i * w01i + w02r * w02r + w02i * w02i
                         + w03r * w03r + w03i * w03i + w12r * w12r + w12i * w12i
                         + w13r * w13r + w13i * w13i + w23r * w23r + w23i * w23i);

        float tr1 = 4.0f * a0;
        float t2 = tr1 * tr1;
        float c2v = t2 - p2;
        float c3v = tr1 * t2 - 3.0f * tr1 * p2 + 2.0f * p3;
        float c4v = t2 * t2 - 6.0f * t2 * p2 + 3.0f * p2 * p2 + 8.0f * tr1 * p3 - 6.0f * p4;
        bool mask = (tr1 >= 0.0f) && (c2v >= 0.0f) && (c3v >= 0.0f) && (c4v >= 0.0f);

        const float SAFE[4][4] = {{1.0f, 0.02f, 0.01f, 0.005f},
                                  {0.0f, 0.95f, 0.05f, 0.0f},
                                  {0.0f, -0.05f, 0.9f, 0.04f},
                                  {0.0f, 0.0f, -0.04f, 0.85f}};
#pragma unroll
        for (int i = 0; i < 4; i++)
#pragma unroll
            for (int j = 0; j < 4; j++) M[i][j] = mask ? M[i][j] : SAFE[i][j];
    }

    // ---- Lu-Chipman ----
    float D0 = M[0][1], D1 = M[0][2], D2v = M[0][3];
    float d2r = D0 * D0 + D1 * D1 + D2v * D2v;
    float totD = fsqrtf_(d2r + 1e-12f);
    float d2 = fminf(fmaxf(d2r, 0.0f), 1.0f - 1e-6f);
    float d = fsqrtf_(d2 + 1e-12f);
    float sq2 = 1.0f - d2;
    float sq = fsqrtf_(sq2);
    float dinv = frcp(fmaxf(d, 1e-6f));
    float h0 = D0 * dinv, h1 = D1 * dinv, h2 = D2v * dinv;

    float isq2 = frcp_nr(sq2);
    float isq = frcp(sq);
    float cdh = (1.0f - sq) * isq2;
    float MDi[4][4];
    MDi[0][0] = isq2;
    MDi[0][1] = -isq2 * D0; MDi[0][2] = -isq2 * D1; MDi[0][3] = -isq2 * D2v;
    MDi[1][0] = MDi[0][1];  MDi[2][0] = MDi[0][2];  MDi[3][0] = MDi[0][3];
    float Dh[3] = {h0, h1, h2};
#pragma unroll
    for (int i = 0; i < 3; i++)
#pragma unroll
        for (int j = 0; j < 3; j++)
            MDi[1 + i][1 + j] = ((i == j) ? isq : 0.0f) + cdh * Dh[i] * Dh[j];

    float Mp[4][4];
    mul4(M, MDi, Mp);

    float mp3[3][3];
#pragma unroll
    for (int i = 0; i < 3; i++)
#pragma unroll
        for (int j = 0; j < 3; j++) mp3[i][j] = Mp[1 + i][1 + j];
    float mmS[3][3];
#pragma unroll
    for (int i = 0; i < 3; i++)
#pragma unroll
        for (int j = 0; j < 3; j++) {
            float s = 0.0f;
#pragma unroll
            for (int k = 0; k < 3; k++) s += mp3[i][k] * mp3[j][k];
            mmS[i][j] = s;
        }
    float l1, l2, l3;
    eig3_sym(mmS, l1, l2, l3);
    l1 = fmaxf(l1, 1e-12f); l2 = fmaxf(l2, 1e-12f); l3 = fmaxf(l3, 1e-12f);
    float s1 = fsqrtf_(l1), s2 = fsqrtf_(l2), s3 = fsqrtf_(l3);
    float sgn = (det3(mp3) < 0.0f) ? -1.0f : 1.0f;

    float e2s = s1 * s2 + s2 * s3 + s3 * s1 + 1e-6f;
    float e1s = s1 + s2 + s3;
    float e3s = s1 * s2 * s3;
    float A3[3][3], B3[3][3];
#pragma unroll
    for (int i = 0; i < 3; i++)
#pragma unroll
        for (int j = 0; j < 3; j++) {
            A3[i][j] = mmS[i][j] + ((i == j) ? e2s : 0.0f);
            B3[i][j] = e1s * mmS[i][j] + ((i == j) ? e3s : 0.0f);
        }
    float A3i[3][3];
    inv3(A3, A3i);
    float mdel[3][3];
#pragma unroll
    for (int i = 0; i < 3; i++)
#pragma unroll
        for (int j = 0; j < 3; j++) {
            float s = 0.0f;
#pragma unroll
            for (int k = 0; k < 3; k++) s += A3i[i][k] * B3[k][j];
            mdel[i][j] = sgn * s;
        }

    float Pd[3];
#pragma unroll
    for (int i = 0; i < 3; i++)
        Pd[i] = (M[1 + i][0] - (M[1 + i][1] * D0 + M[1 + i][2] * D1 + M[1 + i][3] * D2v)) * isq2;

    float MR0[4];
    const float inv_aeps = 1.0f / (1.0f + 1e-6f);
#pragma unroll
    for (int j = 0; j < 4; j++) MR0[j] = Mp[0][j] * inv_aeps;
    float m3[3][3];
#pragma unroll
    for (int i = 0; i < 3; i++)
#pragma unroll
        for (int j = 0; j < 3; j++) m3[i][j] = mdel[i][j] + ((i == j) ? 1e-6f : 0.0f);
    float m3i[3][3];
    inv3(m3, m3i);
    float MRr[3][4];
#pragma unroll
    for (int i = 0; i < 3; i++)
#pragma unroll
        for (int j = 0; j < 4; j++) {
            float s = 0.0f;
#pragma unroll
            for (int k = 0; k < 3; k++) s += m3i[i][k] * (Mp[1 + k][j] - Pd[k] * MR0[j]);
            MRr[i][j] = s;
        }

    float mR00 = MRr[0][1], mR01 = MRr[0][2], mR02 = MRr[0][3];
    float mR10 = MRr[1][1], mR11 = MRr[1][2], mR12 = MRr[1][3];
    float mR20 = MRr[2][1], mR21 = MRr[2][2];

    float t_lin = fsqrtf_((mR00 + mR11) * (mR00 + mR11) + (mR10 - mR01) * (mR10 - mR01) + 1e-12f) - 1.0f;
    t_lin = fminf(fmaxf(t_lin, -1.0f + 1e-6f), 1.0f - 1e-6f);
    float linR = fast_acos(t_lin) * DEG_;

    float azi = 0.5f * fast_atan2(mR20 - mR02, mR12 - mR21) * DEG_;
    if (azi < 0.0f) azi += 180.0f;

    float totP = 1.0f - fabsf(mdel[0][0] + mdel[1][1] + mdel[2][2]) * (1.0f / 3.0f);

    linR_o = linR; totP_o = totP; totD_o = totD; azi_o = azi;
}

// One thread = two ADJACENT pixels (2t, 2t+1): dwordx2 loads/stores.
// W^T loads deferred past the first solve (sched_barrier fence) to cut peak
// VGPR pressure: F+A (64 floats) + solve state vs previously +32 W floats.
__global__ __launch_bounds__(256) void main_kernel(const float* __restrict__ x,
                                                   const unsigned int* __restrict__ mmk,
                                                   float* __restrict__ out) {
    int tid = blockIdx.x * 256 + threadIdx.x;       // 0 .. B_*HW_/2 - 1
    int b = tid / (HW_ / 2);
    int pp = tid - b * (HW_ / 2);
    int p = pp * 2;
    const float* src = x + (size_t)b * NCH_IN * HW_ + p;

    float m[2][4][8];       // [pixel][row][A|F]
#pragma unroll
    for (int i = 0; i < 4; i++)
#pragma unroll
        for (int j = 0; j < 4; j++) {
            f2 f = __builtin_nontemporal_load((const f2*)&src[(size_t)(4 * i + j) * HW_]);
            f2 a = __builtin_nontemporal_load((const f2*)&src[(size_t)(16 + 4 * i + j) * HW_]);
            m[0][i][4 + j] = f.x; m[1][i][4 + j] = f.y;
            m[0][i][j]     = a.x; m[1][i][j]     = a.y;
        }
    float inten0 = m[0][0][4], inten1 = m[1][0][4];

    solve4_dual(m);   // cols 4..7 = X = A^-1 F

    // fence: keep W loads AFTER solve1 so their registers don't overlap its peak
    __builtin_amdgcn_sched_barrier(0);

    float m2[2][4][8];
#pragma unroll
    for (int i = 0; i < 4; i++)
#pragma unroll
        for (int j = 0; j < 4; j++) {
            f2 w = __builtin_nontemporal_load((const f2*)&src[(size_t)(32 + 4 * i + j) * HW_]);
            m2[0][j][i] = w.x;              // W^T
            m2[1][j][i] = w.y;
        }
#pragma unroll
    for (int q = 0; q < 2; q++)
#pragma unroll
        for (int i = 0; i < 4; i++)
#pragma unroll
            for (int j = 0; j < 4; j++)
                m2[q][i][4 + j] = m[q][j][4 + i];   // X^T
    solve4_dual(m2);  // cols 4..7 = M^T

    float M[2][4][4];
#pragma unroll
    for (int q = 0; q < 2; q++) {
        float nrm = frcp_nr(m2[q][0][4]);
#pragma unroll
        for (int i = 0; i < 4; i++)
#pragma unroll
            for (int j = 0; j < 4; j++) M[q][i][j] = m2[q][j][4 + i] * nrm;
    }

    float* ob = out + (size_t)b * NCH_OUT * HW_ + p;
    float imin = funkey(~mmk[2 * b]), imax = funkey(mmk[2 * b + 1]);
    float iscale = frcp(imax - imin);
    {
        f2 v; v.x = (inten0 - imin) * iscale; v.y = (inten1 - imin) * iscale;
        __builtin_nontemporal_store(v, (f2*)&ob[0]);
    }
#pragma unroll
    for (int k = 0; k < 16; k++) {
        f2 v; v.x = M[0][k >> 2][k & 3]; v.y = M[1][k >> 2][k & 3];
        __builtin_nontemporal_store(v, (f2*)&ob[(size_t)(1 + k) * HW_]);
    }

    float linR[2], totP[2], totD[2], azi[2];
#pragma unroll
    for (int q = 0; q < 2; q++)
        pixel_tail(M[q], linR[q], totP[q], totD[q], azi[q]);

    f2 v;
    v.x = linR[0]; v.y = linR[1]; __builtin_nontemporal_store(v, (f2*)&ob[(size_t)17 * HW_]);
    v.x = totP[0]; v.y = totP[1]; __builtin_nontemporal_store(v, (f2*)&ob[(size_t)18 * HW_]);
    v.x = totD[0]; v.y = totD[1]; __builtin_nontemporal_store(v, (f2*)&ob[(size_t)19 * HW_]);
    v.x = azi[0];  v.y = azi[1];  *(f2*)&ob[(size_t)20 * HW_] = v;   // re-read by circstd
}

// fused 8x8 SAME rolling circular-std (pad lo=3 hi=4) over out ch20 -> ch21
#define TX_ 32
#define TY_ 8
__global__ __launch_bounds__(256) void circstd_kernel(float* __restrict__ out) {
    int tx0 = blockIdx.x * TX_;
    int ty0 = blockIdx.y * TY_;
    int b = blockIdx.z;
    const float* azi = out + (size_t)b * NCH_OUT * HW_ + (size_t)20 * HW_;

    __shared__ float lc[TY_ + 7][TX_ + 8];
    __shared__ float ls[TY_ + 7][TX_ + 8];
    __shared__ float hc[TY_ + 7][TX_];
    __shared__ float hs[TY_ + 7][TX_];

    for (int i = threadIdx.x; i < (TY_ + 7) * (TX_ + 7); i += 256) {
        int row = i / (TX_ + 7);
        int col = i - row * (TX_ + 7);
        int gy = ty0 - 3 + row;
        int gx = tx0 - 3 + col;
        float c = 0.0f, s = 0.0f;
        if (gy >= 0 && gy < H_ && gx >= 0 && gx < W_) {
            float th = azi[(size_t)gy * W_ + gx] * 0.03490658503988659f;  // pi/90
            __sincosf(th, &s, &c);
        }
        lc[row][col] = c; ls[row][col] = s;
    }
    __syncthreads();

    for (int i = threadIdx.x; i < (TY_ + 7) * TX_; i += 256) {
        int row = i / TX_;
        int col = i - row * TX_;
        float sc = 0.0f, ss = 0.0f;
#pragma unroll
        for (int d = 0; d < 8; d++) { sc += lc[row][col + d]; ss += ls[row][col + d]; }
        hc[row][col] = sc; hs[row][col] = ss;
    }
    __syncthreads();

    int col = threadIdx.x & (TX_ - 1);
    int row = threadIdx.x >> 5;
    float sc = 0.0f, ss = 0.0f;
#pragma unroll
    for (int k = 0; k < 8; k++) { sc += hc[row + k][col]; ss += hs[row + k][col]; }
    int y = ty0 + row, xc = tx0 + col;
    float rows = (float)(min(y + 5, H_) - max(y - 3, 0));
    float cols = (float)(min(xc + 5, W_) - max(xc - 3, 0));
    float R = fsqrtf_(sc * sc + ss * ss + 1e-12f) * frcp(rows * cols);
    R = fminf(fmaxf(R, 1e-7f), 1.0f - 1e-7f);
    float stdv = 0.5f * fsqrtf_(-2.0f * __logf(R)) * DEG_;
    __builtin_nontemporal_store(stdv,
        &out[(size_t)b * NCH_OUT * HW_ + (size_t)21 * HW_ + (size_t)y * W_ + xc]);
}

extern "C" void kernel_launch(void* const* d_in, const int* in_sizes, int n_in,
                              void* d_out, int out_size, void* d_ws, size_t ws_size,
                              hipStream_t stream) {
    const float* x = (const float*)d_in[0];
    float* out = (float*)d_out;
    unsigned int* mmk = (unsigned int*)d_ws;

    hipMemsetAsync(mmk, 0, 4 * sizeof(unsigned int), stream);
    hipLaunchKernelGGL(minmax_kernel, dim3(64), dim3(256), 0, stream, x, mmk);
    hipLaunchKernelGGL(main_kernel, dim3(B_ * HW_ / 2 / 256), dim3(256), 0, stream, x, mmk, out);
    hipLaunchKernelGGL(circstd_kernel, dim3(W_ / TX_, H_ / TY_, B_), dim3(256), 0, stream, out);
}